// Round 9
// baseline (752.526 us; speedup 1.0000x reference)
//
#include <hip/hip_runtime.h>

// ---------------------------------------------------------------------------
// GATv2 x4 + MLP readout.  CSR-by-dst build once per call, then per layer:
//   k_transform: xl = x@Wl+bl, xr = x@Wr+br  (16 nodes/block, float4 acc)
//   k_edge: fused score + online-softmax + aggregate. One wave per NODE,
//     chunk = 16 edges, NO LDS AT ALL.  Lane = (c4 = lane&15 channel-group,
//     r = lane>>4 edge-subgroup).  Load instr i: quarter-wave r reads the
//     full 256B row of edge 4i+r contiguously into a float4 (16 lines/instr,
//     DMA-equivalent coalescing; R7 lesson: rotated gather DMA explodes HBM).
//     Score = per-lane 4-channel partial dot + butterfly over c4 (offs 1..8).
//     Softmax/denom butterflies only over r (offs 16,32).  Aggregate: 16
//     fma/chunk into a float4; final reduce = offs 16,32; output = ONE
//     coalesced dwordx4 store by the 16 r==0 lanes (full lines, no amp —
//     R8 lesson: 4-lane strided float4 stores doubled WRITE_SIZE).
// CSR build: hist -> scanA -> scanC(+B fused) -> k_scatter (LDS-binned,
//   ~77k spread global atomics) -> k_csr (bucket-local scatter).
// Readout: per-block partial sums (no atomics) + 1-block MLP.
// NOTE: packing requires N <= 65536 (here N = 50000).
// R5 lesson: per-edge global atomics on few lines serialize (~11ns/op).
// ---------------------------------------------------------------------------

__device__ __forceinline__ int rfl(int v) { return __builtin_amdgcn_readfirstlane(v); }

__global__ void k_hist(const int* __restrict__ dst, int* __restrict__ deg, int E) {
  int e = blockIdx.x * blockDim.x + threadIdx.x;
  if (e < E) atomicAdd(&deg[dst[e]], 1);
}

// ---- scan pass A: per-1024-chunk sums
__global__ void __launch_bounds__(256) k_scanA(const int* __restrict__ deg,
                                               int* __restrict__ bsum, int n) {
  __shared__ int ws[4];
  int tid = threadIdx.x, lane = tid & 63, wv = tid >> 6;
  int base = blockIdx.x * 1024 + tid;
  int s = 0;
  #pragma unroll
  for (int k = 0; k < 4; k++) {
    int i = base + k * 256;
    if (i < n) s += deg[i];
  }
  #pragma unroll
  for (int o = 32; o > 0; o >>= 1) s += __shfl_xor(s, o, 64);
  if (lane == 0) ws[wv] = s;
  __syncthreads();
  if (tid == 0) bsum[blockIdx.x] = ws[0] + ws[1] + ws[2] + ws[3];
}

// ---- scan pass C (with pass B folded in: every block re-scans bsum)
__global__ void __launch_bounds__(256) k_scanC(const int* __restrict__ deg,
                                               const int* __restrict__ bsum,
                                               int* __restrict__ rowptr, int n, int nb) {
  __shared__ int wtot[4];
  __shared__ int sboff;
  int tid = threadIdx.x, lane = tid & 63, wv = tid >> 6;
  if (wv == 0) {
    int v = (lane < nb) ? bsum[lane] : 0;  // nb <= 64
    int x = v;
    #pragma unroll
    for (int o = 1; o < 64; o <<= 1) {
      int t = __shfl_up(x, o, 64);
      if (lane >= o) x += t;
    }
    if (lane == (int)blockIdx.x) sboff = x - v;        // this block's prefix
    if (blockIdx.x == 0 && lane == 63) rowptr[n] = x;  // grand total
  }
  __syncthreads();
  int i0 = blockIdx.x * 1024 + tid * 4;
  int4 v = make_int4(0, 0, 0, 0);
  if (i0 + 3 < n) v = *(const int4*)(deg + i0);
  else {
    if (i0 + 0 < n) v.x = deg[i0 + 0];
    if (i0 + 1 < n) v.y = deg[i0 + 1];
    if (i0 + 2 < n) v.z = deg[i0 + 2];
  }
  int s = v.x + v.y + v.z + v.w;
  int x = s;
  #pragma unroll
  for (int o = 1; o < 64; o <<= 1) {
    int t = __shfl_up(x, o, 64);
    if (lane >= o) x += t;
  }
  if (lane == 63) wtot[wv] = x;
  __syncthreads();
  int wexcl = 0;
  for (int k = 0; k < 4; k++) if (k < wv) wexcl += wtot[k];
  int excl = sboff + wexcl + (x - s);
  int4 o4;
  o4.x = excl; o4.y = o4.x + v.x; o4.z = o4.y + v.y; o4.w = o4.z + v.z;
  if (i0 + 3 < n) *(int4*)(rowptr + i0) = o4;
  else {
    if (i0 + 0 < n) rowptr[i0 + 0] = o4.x;
    if (i0 + 1 < n) rowptr[i0 + 1] = o4.y;
    if (i0 + 2 < n) rowptr[i0 + 2] = o4.z;
  }
}

// ---- pass 1: block-binned scatter into bucket regions (256 dst per bucket)
#define NBK_MAX 256
__global__ void __launch_bounds__(256) k_scatter(
    const int* __restrict__ src, const int* __restrict__ dst,
    const float* __restrict__ ea_in, const int* __restrict__ rowptr,
    int* __restrict__ bcur, uint2* __restrict__ tmp, int E, int nbk) {
  __shared__ int cnt[NBK_MAX];
  __shared__ int cur[NBK_MAX];
  __shared__ int gbase[NBK_MAX];
  __shared__ int sbase[NBK_MAX];
  int tid = threadIdx.x;
  if (tid < nbk) {
    cnt[tid] = 0;
    cur[tid] = 0;
    sbase[tid] = rowptr[tid << 8];
  }
  __syncthreads();
  int base = blockIdx.x * 4096 + tid;
  uint2 rec[16];
  #pragma unroll
  for (int k = 0; k < 16; k++) {
    int e = base + k * 256;
    if (e < E) {
      unsigned d = (unsigned)dst[e];
      rec[k] = make_uint2((d << 16) | (unsigned)src[e],
                          (unsigned)__float_as_int(ea_in[e]));
      atomicAdd(&cnt[d >> 8], 1);
    } else {
      rec[k] = make_uint2(0u, 0u);
    }
  }
  __syncthreads();
  if (tid < nbk) {
    int c = cnt[tid];
    gbase[tid] = (c > 0) ? atomicAdd(&bcur[tid * 16], c) : 0;
  }
  __syncthreads();
  #pragma unroll
  for (int k = 0; k < 16; k++) {
    int e = base + k * 256;
    if (e < E) {
      int b = (int)(rec[k].x >> 24);
      int slot = atomicAdd(&cur[b], 1);
      tmp[sbase[b] + gbase[b] + slot] = rec[k];
    }
  }
}

// ---- pass 2: one block per bucket; LDS cursors; L2-resident final scatter
__global__ void __launch_bounds__(256) k_csr(const int* __restrict__ rowptr,
                                             const uint2* __restrict__ tmp,
                                             int2* __restrict__ pairs, int N) {
  __shared__ int sRP[257];
  __shared__ int cur[256];
  int b = blockIdx.x;
  int n0 = b << 8;
  int tid = threadIdx.x;
  sRP[tid] = rowptr[min(n0 + tid, N)];
  if (tid == 0) sRP[256] = rowptr[min(n0 + 256, N)];
  cur[tid] = 0;
  __syncthreads();
  int lo = sRP[0], hi = sRP[256];
  for (int k = lo + tid; k < hi; k += 256) {
    uint2 rec = tmp[k];
    int local = (int)(rec.x >> 16) - n0;
    int pos = sRP[local] + atomicAdd(&cur[local], 1);
    pairs[pos] = make_int2((int)(rec.x & 0xffffu), (int)rec.y);
  }
}

// xl = x @ Wl + bl ; xr = x @ Wr + br.  16 nodes/block (R6-proven version).
template <int DIN>
__global__ void __launch_bounds__(256) k_transform(
    const float* __restrict__ x, const float* __restrict__ Wl, const float* __restrict__ bl,
    const float* __restrict__ Wr, const float* __restrict__ br,
    float* __restrict__ xl, float* __restrict__ xr, int nNodes) {
  __shared__ __align__(16) float sWl[DIN * 64];
  __shared__ __align__(16) float sWr[DIN * 64];
  __shared__ float sx[16][DIN + 1];
  int tid = threadIdx.x;
  for (int i = tid; i < DIN * 64; i += 256) { sWl[i] = Wl[i]; sWr[i] = Wr[i]; }
  int nb = blockIdx.x * 16;
  for (int i = tid; i < 16 * DIN; i += 256) {
    int ln = i / DIN, c = i % DIN;
    int g = nb + ln;
    sx[ln][c] = (g < nNodes) ? x[(size_t)g * DIN + c] : 0.f;
  }
  __syncthreads();
  int node = tid >> 4;          // 0..15
  int t4 = (tid & 15) * 4;      // col group
  float4 accl = *(const float4*)(bl + t4);
  float4 accr = *(const float4*)(br + t4);
  const float* xrow = sx[node];
  #pragma unroll 4
  for (int k = 0; k < DIN; k++) {
    float xv = xrow[k];
    float4 wl = *(const float4*)(sWl + k * 64 + t4);
    float4 wr = *(const float4*)(sWr + k * 64 + t4);
    accl.x = fmaf(xv, wl.x, accl.x); accl.y = fmaf(xv, wl.y, accl.y);
    accl.z = fmaf(xv, wl.z, accl.z); accl.w = fmaf(xv, wl.w, accl.w);
    accr.x = fmaf(xv, wr.x, accr.x); accr.y = fmaf(xv, wr.y, accr.y);
    accr.z = fmaf(xv, wr.z, accr.z); accr.w = fmaf(xv, wr.w, accr.w);
  }
  int g = nb + node;
  if (g < nNodes) {
    *(float4*)(xl + (size_t)g * 64 + t4) = accl;
    *(float4*)(xr + (size_t)g * 64 + t4) = accr;
  }
}

// Fused score + online softmax + aggregate.  One wave per node, chunk = 16,
// zero LDS.  Lane = (c4 = lane&15, r = lane>>4); lane handles channels
// [4*c4, 4*c4+4) of edges {r, r+4, r+8, r+12}.
#define SC1(T, EA, OUT) { float u, acc; \
  u = T.x + fmaf(EA, We4.x, xr4.x); u = fmaxf(u, 0.2f * u); acc = at4.x * u; \
  u = T.y + fmaf(EA, We4.y, xr4.y); u = fmaxf(u, 0.2f * u); acc = fmaf(at4.y, u, acc); \
  u = T.z + fmaf(EA, We4.z, xr4.z); u = fmaxf(u, 0.2f * u); acc = fmaf(at4.z, u, acc); \
  u = T.w + fmaf(EA, We4.w, xr4.w); u = fmaxf(u, 0.2f * u); acc = fmaf(at4.w, u, acc); \
  OUT = acc; }

__global__ void __launch_bounds__(256, 8) k_edge(
    const float* __restrict__ xl, const float* __restrict__ xr,
    const int* __restrict__ rowptr, const int* __restrict__ pairs,  // int2 as int*
    const float* __restrict__ We, const float* __restrict__ att,
    const float* __restrict__ bo, float* __restrict__ xout, int nNodes) {
  int lane = threadIdx.x & 63;
  int wv = rfl((int)(threadIdx.x >> 6));
  int n = rfl(blockIdx.x * 4 + wv);
  if (n >= nNodes) return;
  int c4 = lane & 15;   // channel group
  int r  = lane >> 4;   // edge subgroup (0..3)
  int cb = c4 * 4;      // first channel

  float4 We4 = *(const float4*)(We + cb);
  float4 at4 = *(const float4*)(att + cb);
  float4 xr4 = *(const float4*)(xr + (size_t)n * 64 + cb);
  int s0 = rfl(rowptr[n]);
  int s1 = rfl(rowptr[n + 1]);

  float m = -3.0e38f, d = 0.f;
  float4 A = {0.f, 0.f, 0.f, 0.f};

  for (int kb = s0; kb < s1; kb += 16) {
    int cnt = rfl(min(16, s1 - kb));
    int raw = 0;
    if (lane < 2 * cnt) raw = pairs[2 * kb + lane];  // 16 int2 in lanes 0..31

    // ---- gather rows straight to registers: instr i = edge 4i+r,
    // quarter-wave r reads the row contiguously (c4*16B) -> coalesced.
    int sA = __shfl(raw, 2 * r, 64);
    int sB = __shfl(raw, 8 + 2 * r, 64);
    int sC = __shfl(raw, 16 + 2 * r, 64);
    int sD = __shfl(raw, 24 + 2 * r, 64);
    float ea0 = __int_as_float(__shfl(raw, 2 * r + 1, 64));
    float ea1 = __int_as_float(__shfl(raw, 8 + 2 * r + 1, 64));
    float ea2 = __int_as_float(__shfl(raw, 16 + 2 * r + 1, 64));
    float ea3 = __int_as_float(__shfl(raw, 24 + 2 * r + 1, 64));
    float4 t0 = *(const float4*)(xl + (size_t)(unsigned)sA * 64 + cb);
    float4 t1 = *(const float4*)(xl + (size_t)(unsigned)sB * 64 + cb);
    float4 t2 = *(const float4*)(xl + (size_t)(unsigned)sC * 64 + cb);
    float4 t3 = *(const float4*)(xl + (size_t)(unsigned)sD * 64 + cb);

    // ---- per-lane 4-channel partial dots (padded edges read node 0: valid)
    float sc0, sc1, sc2, sc3;
    SC1(t0, ea0, sc0)
    SC1(t1, ea1, sc1)
    SC1(t2, ea2, sc2)
    SC1(t3, ea3, sc3)

    // complete the dots: butterfly over the 16 c4-lanes
    #pragma unroll
    for (int o = 1; o <= 8; o <<= 1) {
      sc0 += __shfl_xor(sc0, o, 64);
      sc1 += __shfl_xor(sc1, o, 64);
      sc2 += __shfl_xor(sc2, o, 64);
      sc3 += __shfl_xor(sc3, o, 64);
    }
    // mask padded edges (j = 4i + r >= cnt) -> alpha 0
    sc0 = (r < cnt)      ? sc0 : -3.0e38f;
    sc1 = (4 + r < cnt)  ? sc1 : -3.0e38f;
    sc2 = (8 + r < cnt)  ? sc2 : -3.0e38f;
    sc3 = (12 + r < cnt) ? sc3 : -3.0e38f;

    // ---- online softmax (cross-lane only over r: offsets 16, 32)
    float mc = fmaxf(fmaxf(sc0, sc1), fmaxf(sc2, sc3));
    mc = fmaxf(mc, __shfl_xor(mc, 16, 64));
    mc = fmaxf(mc, __shfl_xor(mc, 32, 64));
    float newm = fmaxf(m, mc);
    float rf = expf(m - newm);       // 0 on first chunk, 1 if max unchanged
    float a0 = expf(sc0 - newm);
    float a1 = expf(sc1 - newm);
    float a2 = expf(sc2 - newm);
    float a3 = expf(sc3 - newm);
    float ds = (a0 + a1) + (a2 + a3);
    ds += __shfl_xor(ds, 16, 64);
    ds += __shfl_xor(ds, 32, 64);
    d = d * rf + ds;
    m = newm;

    // ---- aggregate in registers
    A.x = A.x * rf; A.y = A.y * rf; A.z = A.z * rf; A.w = A.w * rf;
    A.x = fmaf(a0, t0.x, A.x); A.y = fmaf(a0, t0.y, A.y);
    A.z = fmaf(a0, t0.z, A.z); A.w = fmaf(a0, t0.w, A.w);
    A.x = fmaf(a1, t1.x, A.x); A.y = fmaf(a1, t1.y, A.y);
    A.z = fmaf(a1, t1.z, A.z); A.w = fmaf(a1, t1.w, A.w);
    A.x = fmaf(a2, t2.x, A.x); A.y = fmaf(a2, t2.y, A.y);
    A.z = fmaf(a2, t2.z, A.z); A.w = fmaf(a2, t2.w, A.w);
    A.x = fmaf(a3, t3.x, A.x); A.y = fmaf(a3, t3.y, A.y);
    A.z = fmaf(a3, t3.z, A.z); A.w = fmaf(a3, t3.w, A.w);
  }

  // combine the 4 r-subgroups (channels are per-lane, edges were split by r)
  A.x += __shfl_xor(A.x, 16, 64); A.y += __shfl_xor(A.y, 16, 64);
  A.z += __shfl_xor(A.z, 16, 64); A.w += __shfl_xor(A.w, 16, 64);
  A.x += __shfl_xor(A.x, 32, 64); A.y += __shfl_xor(A.y, 32, 64);
  A.z += __shfl_xor(A.z, 32, 64); A.w += __shfl_xor(A.w, 32, 64);

  float inv = 1.f / (d + 1e-16f);
  if (r == 0) {  // 16 lanes, contiguous 256B -> one coalesced dwordx4 store
    float4 bo4 = *(const float4*)(bo + cb);
    float4 o4;
    o4.x = fmaxf(fmaf(A.x, inv, bo4.x), 0.f);
    o4.y = fmaxf(fmaf(A.y, inv, bo4.y), 0.f);
    o4.z = fmaxf(fmaf(A.z, inv, bo4.z), 0.f);
    o4.w = fmaxf(fmaf(A.w, inv, bo4.w), 0.f);
    *(float4*)(xout + (size_t)n * 64 + cb) = o4;
  }
}

// per-block partial sums (no atomics); k_mlp reduces the 64 partials
__global__ void k_mean(const float* __restrict__ x, float* __restrict__ part, int nNodes) {
  __shared__ float sacc[256];
  int lane = threadIdx.x & 63;
  int gw = blockIdx.x * 4 + (threadIdx.x >> 6);
  int stride = gridDim.x * 4;
  float acc = 0.f;
  for (int n = gw; n < nNodes; n += stride) acc += x[(size_t)n * 64 + lane];
  sacc[threadIdx.x] = acc;
  __syncthreads();
  if (threadIdx.x < 64)
    part[blockIdx.x * 64 + threadIdx.x] =
        sacc[threadIdx.x] + sacc[threadIdx.x + 64] + sacc[threadIdx.x + 128] + sacc[threadIdx.x + 192];
}

__global__ void k_mlp(const float* __restrict__ part, int nparts,
                      const float* __restrict__ Wm1, const float* __restrict__ bm1,
                      const float* __restrict__ Wm2, const float* __restrict__ bm2,
                      const float* __restrict__ Wm3, const float* __restrict__ bm3,
                      float* __restrict__ out, double invN) {
  __shared__ float xm[64];
  __shared__ float h1[32];
  __shared__ float h2[16];
  int t = threadIdx.x;
  double s = 0.0;
  for (int b = 0; b < nparts; b++) s += (double)part[b * 64 + t];
  xm[t] = (float)(s * invN);
  __syncthreads();
  if (t < 32) {
    float a = bm1[t];
    for (int c = 0; c < 64; c++) a = fmaf(xm[c], Wm1[c * 32 + t], a);
    h1[t] = fmaxf(a, 0.f);
  }
  __syncthreads();
  if (t < 16) {
    float a = bm2[t];
    for (int c = 0; c < 32; c++) a = fmaf(h1[c], Wm2[c * 16 + t], a);
    h2[t] = fmaxf(a, 0.f);
  }
  __syncthreads();
  if (t == 0) {
    float a = bm3[0];
    for (int c = 0; c < 16; c++) a = fmaf(h2[c], Wm3[c], a);
    out[0] = a;
  }
}

extern "C" void kernel_launch(void* const* d_in, const int* in_sizes, int n_in,
                              void* d_out, int out_size, void* d_ws, size_t ws_size,
                              hipStream_t stream) {
  (void)n_in; (void)out_size; (void)ws_size;
  const int N = in_sizes[0] / 36;   // 50000
  const int E = in_sizes[1];        // 1600000

  const float* feat = (const float*)d_in[0];
  const float* eat  = (const float*)d_in[1];
  const int*   eidx = (const int*)d_in[2];
  const int* src = eidx;
  const int* dst = eidx + E;

  const float* L[4][7];  // Wl, bl, Wr, br, We, att, bo
  for (int l = 0; l < 4; l++)
    for (int j = 0; j < 7; j++) L[l][j] = (const float*)d_in[3 + l * 7 + j];
  const float* Wm1 = (const float*)d_in[31];
  const float* bm1 = (const float*)d_in[32];
  const float* Wm2 = (const float*)d_in[33];
  const float* bm2 = (const float*)d_in[34];
  const float* Wm3 = (const float*)d_in[35];
  const float* bm3 = (const float*)d_in[36];

  const int NBK = (N + 255) >> 8;  // buckets of 256 dst nodes (196)

  // workspace layout (512B aligned)
  char* ws = (char*)d_ws;
  size_t off = 0;
  auto alloc = [&](size_t bytes) {
    off = (off + 511) & ~(size_t)511;
    void* p = ws + off;
    off += bytes;
    return p;
  };
  int*    deg     = (int*)alloc((size_t)N * 4);
  int*    bcur    = (int*)alloc((size_t)NBK * 16 * 4);  // 1 counter per 64B line
  size_t zero_bytes = off;  // deg + bcur
  int*    rowptr  = (int*)alloc((size_t)(N + 1) * 4);
  int*    bsum    = (int*)alloc(64 * 4);
  float*  part    = (float*)alloc(64 * 64 * 4);
  int2*   pairs   = (int2*)alloc((size_t)E * 8);
  float*  xA      = (float*)alloc((size_t)N * 64 * 4);  // xl
  float*  xB      = (float*)alloc((size_t)N * 64 * 4);  // xr
  float*  xC      = (float*)alloc((size_t)N * 64 * 4);  // layer out / next in
  uint2*  tmp     = (uint2*)xC;  // aliases xC: dead until k_edge layer 1 writes it

  hipMemsetAsync(d_ws, 0, zero_bytes, stream);

  int egrid = (E + 255) / 256;
  int sgrid = (E + 4095) / 4096; // k_scatter: 4096 edges per 256-thr block
  int tgrid = (N + 15) / 16;     // k_transform: 16 nodes per 256-thr block
  int ngrid = (N + 3) / 4;       // k_edge: 4 nodes (waves) per 256-thr block
  int nb = (N + 1023) / 1024;    // scan blocks (49 <= 64)

  k_hist<<<egrid, 256, 0, stream>>>(dst, deg, E);
  k_scanA<<<nb, 256, 0, stream>>>(deg, bsum, N);
  k_scanC<<<nb, 256, 0, stream>>>(deg, bsum, rowptr, N, nb);
  k_scatter<<<sgrid, 256, 0, stream>>>(src, dst, eat, rowptr, bcur, tmp, E, NBK);
  k_csr<<<NBK, 256, 0, stream>>>(rowptr, tmp, pairs, N);

  for (int l = 0; l < 4; l++) {
    if (l == 0)
      k_transform<36><<<tgrid, 256, 0, stream>>>(feat, L[0][0], L[0][1], L[0][2], L[0][3], xA, xB, N);
    else
      k_transform<64><<<tgrid, 256, 0, stream>>>(xC, L[l][0], L[l][1], L[l][2], L[l][3], xA, xB, N);
    k_edge<<<ngrid, 256, 0, stream>>>(xA, xB, rowptr, (const int*)pairs,
                                      L[l][4], L[l][5], L[l][6], xC, N);
  }

  k_mean<<<64, 256, 0, stream>>>(xC, part, N);
  k_mlp<<<1, 64, 0, stream>>>(part, 64, Wm1, bm1, Wm2, bm2, Wm3, bm3,
                              (float*)d_out, 1.0 / (double)N);
}

// Round 10
// 629.329 us; speedup vs baseline: 1.1958x; 1.1958x over previous
//
#include <hip/hip_runtime.h>

// ---------------------------------------------------------------------------
// GATv2 x4 + MLP readout.  R10 = R6-proven build + weight-reuse transform.
//   k_transform: weights staged ONCE per block, 4 tiles x 16 nodes looped
//     (R6 staged per 16-node block: 100 MB/layer of L2 weight traffic).
//   k_edge (R6 verbatim, 72.5us measured): one wave per NODE, chunk = 16.
//     Wave-uniform global_load_lds per row into stride-68 tile (R7/R9
//     lesson: any per-lane-gather staging explodes HBM traffic).  Score
//     lane=(e,q) dots 16 channels via b128 tile reads; aggregate is
//     lane=channel with readlane alphas (R8 lesson: register-agg + per-node
//     128-op butterfly costs more than 16 ds_read_b32/chunk at deg~32).
// CSR build: hist -> scanA/B/C -> k_scatter (LDS-binned, ~77k spread global
//   atomics; R5 lesson: per-edge atomics on few lines serialize ~11ns/op)
//   -> k_csr (bucket-local L2-resident scatter).
// Readout: f64-atomic mean + 1-block MLP.   N <= 65536 packing assumption.
// ---------------------------------------------------------------------------

__device__ __forceinline__ float readlane_f(float v, int l) {
  return __int_as_float(__builtin_amdgcn_readlane(__float_as_int(v), l));
}
__device__ __forceinline__ int rfl(int v) { return __builtin_amdgcn_readfirstlane(v); }

__device__ __forceinline__ void row_to_lds(const float* g, float* l) {
  __builtin_amdgcn_global_load_lds((const __attribute__((address_space(1))) void*)g,
                                   (__attribute__((address_space(3))) void*)l,
                                   4, 0, 0);
}

__global__ void k_hist(const int* __restrict__ dst, int* __restrict__ deg, int E) {
  int e = blockIdx.x * blockDim.x + threadIdx.x;
  if (e < E) atomicAdd(&deg[dst[e]], 1);
}

// ---- parallel exclusive scan over n ints: A (block sums), B (scan sums), C
__global__ void __launch_bounds__(256) k_scanA(const int* __restrict__ deg,
                                               int* __restrict__ bsum, int n) {
  __shared__ int ws[4];
  int tid = threadIdx.x, lane = tid & 63, wv = tid >> 6;
  int base = blockIdx.x * 1024 + tid;
  int s = 0;
  #pragma unroll
  for (int k = 0; k < 4; k++) {
    int i = base + k * 256;
    if (i < n) s += deg[i];
  }
  #pragma unroll
  for (int o = 32; o > 0; o >>= 1) s += __shfl_xor(s, o, 64);
  if (lane == 0) ws[wv] = s;
  __syncthreads();
  if (tid == 0) bsum[blockIdx.x] = ws[0] + ws[1] + ws[2] + ws[3];
}

__global__ void k_scanB(const int* __restrict__ bsum, int* __restrict__ boffs,
                        int* __restrict__ rowptr, int nb, int n) {
  int lane = threadIdx.x;  // 64 threads, nb <= 64
  int v = (lane < nb) ? bsum[lane] : 0;
  int x = v;
  #pragma unroll
  for (int o = 1; o < 64; o <<= 1) {
    int t = __shfl_up(x, o, 64);
    if (lane >= o) x += t;
  }
  if (lane < nb) boffs[lane] = x - v;
  if (lane == 63) rowptr[n] = x;
}

__global__ void __launch_bounds__(256) k_scanC(const int* __restrict__ deg,
                                               const int* __restrict__ boffs,
                                               int* __restrict__ rowptr, int n) {
  __shared__ int wtot[4];
  int tid = threadIdx.x, lane = tid & 63, wv = tid >> 6;
  int i0 = blockIdx.x * 1024 + tid * 4;
  int4 v = make_int4(0, 0, 0, 0);
  if (i0 + 3 < n) v = *(const int4*)(deg + i0);
  else {
    if (i0 + 0 < n) v.x = deg[i0 + 0];
    if (i0 + 1 < n) v.y = deg[i0 + 1];
    if (i0 + 2 < n) v.z = deg[i0 + 2];
  }
  int s = v.x + v.y + v.z + v.w;
  int x = s;
  #pragma unroll
  for (int o = 1; o < 64; o <<= 1) {
    int t = __shfl_up(x, o, 64);
    if (lane >= o) x += t;
  }
  if (lane == 63) wtot[wv] = x;
  __syncthreads();
  int wexcl = 0;
  for (int k = 0; k < 4; k++) if (k < wv) wexcl += wtot[k];
  int excl = boffs[blockIdx.x] + wexcl + (x - s);
  int4 o4;
  o4.x = excl; o4.y = o4.x + v.x; o4.z = o4.y + v.y; o4.w = o4.z + v.z;
  if (i0 + 3 < n) *(int4*)(rowptr + i0) = o4;
  else {
    if (i0 + 0 < n) rowptr[i0 + 0] = o4.x;
    if (i0 + 1 < n) rowptr[i0 + 1] = o4.y;
    if (i0 + 2 < n) rowptr[i0 + 2] = o4.z;
  }
}

// ---- pass 1: block-binned scatter into bucket regions (256 dst per bucket)
#define NBK_MAX 256
__global__ void __launch_bounds__(256) k_scatter(
    const int* __restrict__ src, const int* __restrict__ dst,
    const float* __restrict__ ea_in, const int* __restrict__ rowptr,
    int* __restrict__ bcur, uint2* __restrict__ tmp, int E, int nbk) {
  __shared__ int cnt[NBK_MAX];
  __shared__ int cur[NBK_MAX];
  __shared__ int gbase[NBK_MAX];
  __shared__ int sbase[NBK_MAX];
  int tid = threadIdx.x;
  if (tid < nbk) {
    cnt[tid] = 0;
    cur[tid] = 0;
    sbase[tid] = rowptr[tid << 8];
  }
  __syncthreads();
  int base = blockIdx.x * 4096 + tid;
  uint2 rec[16];
  #pragma unroll
  for (int k = 0; k < 16; k++) {
    int e = base + k * 256;
    if (e < E) {
      unsigned d = (unsigned)dst[e];
      rec[k] = make_uint2((d << 16) | (unsigned)src[e],
                          (unsigned)__float_as_int(ea_in[e]));
      atomicAdd(&cnt[d >> 8], 1);
    } else {
      rec[k] = make_uint2(0u, 0u);
    }
  }
  __syncthreads();
  if (tid < nbk) {
    int c = cnt[tid];
    gbase[tid] = (c > 0) ? atomicAdd(&bcur[tid * 16], c) : 0;
  }
  __syncthreads();
  #pragma unroll
  for (int k = 0; k < 16; k++) {
    int e = base + k * 256;
    if (e < E) {
      int b = (int)(rec[k].x >> 24);
      int slot = atomicAdd(&cur[b], 1);
      tmp[sbase[b] + gbase[b] + slot] = rec[k];
    }
  }
}

// ---- pass 2: one block per bucket; LDS cursors; L2-resident final scatter
__global__ void __launch_bounds__(256) k_csr(const int* __restrict__ rowptr,
                                             const uint2* __restrict__ tmp,
                                             int2* __restrict__ pairs, int N) {
  __shared__ int sRP[257];
  __shared__ int cur[256];
  int b = blockIdx.x;
  int n0 = b << 8;
  int tid = threadIdx.x;
  sRP[tid] = rowptr[min(n0 + tid, N)];
  if (tid == 0) sRP[256] = rowptr[min(n0 + 256, N)];
  cur[tid] = 0;
  __syncthreads();
  int lo = sRP[0], hi = sRP[256];
  for (int k = lo + tid; k < hi; k += 256) {
    uint2 rec = tmp[k];
    int local = (int)(rec.x >> 16) - n0;
    int pos = sRP[local] + atomicAdd(&cur[local], 1);
    pairs[pos] = make_int2((int)(rec.x & 0xffffu), (int)rec.y);
  }
}

// xl = x @ Wl + bl ; xr = x @ Wr + br.  R6 inner structure (1 node x 4 cols
// per thread, 16-node tiles) but weights staged ONCE per block and reused
// across TILES tiles (R6: 3125 blocks x 32KB = 100MB/layer weight traffic).
template <int DIN, int TILES>
__global__ void __launch_bounds__(256) k_transform(
    const float* __restrict__ x, const float* __restrict__ Wl, const float* __restrict__ bl,
    const float* __restrict__ Wr, const float* __restrict__ br,
    float* __restrict__ xl, float* __restrict__ xr, int nNodes) {
  __shared__ __align__(16) float sWl[DIN * 64];
  __shared__ __align__(16) float sWr[DIN * 64];
  __shared__ float sx[16][DIN + 1];
  int tid = threadIdx.x;
  for (int i = tid; i < DIN * 64; i += 256) { sWl[i] = Wl[i]; sWr[i] = Wr[i]; }
  int node = tid >> 4;          // 0..15
  int t4 = (tid & 15) * 4;      // col group
  float4 bl4 = *(const float4*)(bl + t4);
  float4 br4 = *(const float4*)(br + t4);
  for (int t = 0; t < TILES; t++) {
    int nb = (blockIdx.x * TILES + t) * 16;
    if (nb >= nNodes) break;    // uniform across block
    __syncthreads();            // weights ready / previous tile consumed
    for (int i = tid; i < 16 * DIN; i += 256) {
      int ln = i / DIN, c = i % DIN;
      int g = nb + ln;
      sx[ln][c] = (g < nNodes) ? x[(size_t)g * DIN + c] : 0.f;
    }
    __syncthreads();
    float4 accl = bl4;
    float4 accr = br4;
    const float* xrow = sx[node];
    #pragma unroll 4
    for (int k = 0; k < DIN; k++) {
      float xv = xrow[k];
      float4 wl = *(const float4*)(sWl + k * 64 + t4);
      float4 wr = *(const float4*)(sWr + k * 64 + t4);
      accl.x = fmaf(xv, wl.x, accl.x); accl.y = fmaf(xv, wl.y, accl.y);
      accl.z = fmaf(xv, wl.z, accl.z); accl.w = fmaf(xv, wl.w, accl.w);
      accr.x = fmaf(xv, wr.x, accr.x); accr.y = fmaf(xv, wr.y, accr.y);
      accr.z = fmaf(xv, wr.z, accr.z); accr.w = fmaf(xv, wr.w, accr.w);
    }
    int g = nb + node;
    if (g < nNodes) {
      *(float4*)(xl + (size_t)g * 64 + t4) = accl;
      *(float4*)(xr + (size_t)g * 64 + t4) = accr;
    }
  }
}

// Fused score + online softmax + aggregate. One wave per node, chunk = 16.
// R6 verbatim (72.5 us measured).
__global__ void __launch_bounds__(256, 8) k_edge(
    const float* __restrict__ xl, const float* __restrict__ xr,
    const int* __restrict__ rowptr, const int* __restrict__ pairs,  // int2 as int*
    const float* __restrict__ We, const float* __restrict__ att,
    const float* __restrict__ bo, float* __restrict__ xout, int nNodes) {
  __shared__ __align__(16) float tile[4][16 * 68];  // 4.35 KB per wave
  __shared__ __align__(16) float sXr[4][64];
  __shared__ __align__(16) float sWe[64];
  __shared__ __align__(16) float sAtt[64];
  int tid = threadIdx.x;
  int lane = tid & 63;
  int wv = rfl(tid >> 6);
  int n = rfl(blockIdx.x * 4 + wv);
  if (tid < 64) { sWe[tid] = We[tid]; sAtt[tid] = att[tid]; }
  bool active = (n < nNodes);
  if (active) sXr[wv][lane] = xr[(size_t)n * 64 + lane];
  __syncthreads();
  if (!active) return;

  float* tw = tile[wv];
  int s0 = rfl(rowptr[n]);
  int s1 = rfl(rowptr[n + 1]);
  int e = lane & 15, q = lane >> 4;
  const float* xq = sXr[wv] + q * 16;
  const float* wq = sWe + q * 16;
  const float* aq = sAtt + q * 16;

  float m = -3.0e38f, d = 0.f, acc0 = 0.f, acc1 = 0.f;

  for (int kb = s0; kb < s1; kb += 16) {
    int cnt = rfl(min(16, s1 - kb));
    // pairs chunk: int2 elements [kb, kb+cnt) read raw by 2*cnt lanes
    int raw = 0;
    if (lane < 2 * cnt) raw = pairs[2 * kb + lane];
    float ea = __int_as_float(__shfl(raw, 2 * e + 1, 64));  // ea of my edge

    // ---- stage xl rows of this chunk into LDS (async DMA, 1 instr/row)
    for (int j = 0; j < cnt; ++j) {
      int s = __builtin_amdgcn_readlane(raw, 2 * j);
      row_to_lds(xl + (size_t)(unsigned)s * 64 + lane, tw + j * 68);
    }
    __builtin_amdgcn_s_waitcnt(0);

    // ---- score: lane (e,q) dots channels [16q,16q+16) of edge e.
    // All non-tile operands come from LDS (broadcast); no VMEM here.
    const float* trow = tw + e * 68 + q * 16;
    float sc = 0.f;
    #pragma unroll 2
    for (int g = 0; g < 4; ++g) {
      float4 tv = *(const float4*)(trow + 4 * g);
      float4 xv = *(const float4*)(xq + 4 * g);
      float4 wvv = *(const float4*)(wq + 4 * g);
      float4 av = *(const float4*)(aq + 4 * g);
      float u;
      u = tv.x + fmaf(ea, wvv.x, xv.x); u = fmaxf(u, 0.2f * u); sc = fmaf(av.x, u, sc);
      u = tv.y + fmaf(ea, wvv.y, xv.y); u = fmaxf(u, 0.2f * u); sc = fmaf(av.y, u, sc);
      u = tv.z + fmaf(ea, wvv.z, xv.z); u = fmaxf(u, 0.2f * u); sc = fmaf(av.z, u, sc);
      u = tv.w + fmaf(ea, wvv.w, xv.w); u = fmaxf(u, 0.2f * u); sc = fmaf(av.w, u, sc);
    }
    sc += __shfl_xor(sc, 16, 64);          // combine the 4 channel quarters
    sc += __shfl_xor(sc, 32, 64);
    sc = (e < cnt) ? sc : -3.0e38f;        // padded edges -> alpha = 0

    // ---- online softmax over 16 edges (quarter-duplicated lanes)
    float mc = sc;
    #pragma unroll
    for (int o = 1; o <= 8; o <<= 1) mc = fmaxf(mc, __shfl_xor(mc, o, 64));
    float newm = fmaxf(m, mc);
    float r = expf(m - newm);              // 0 on first chunk, 1 if max unchanged
    float alpha = expf(sc - newm);
    float ds = alpha;
    #pragma unroll
    for (int o = 1; o <= 8; o <<= 1) ds += __shfl_xor(ds, o, 64);
    d = d * r + ds;
    acc0 *= r; acc1 *= r;
    m = newm;

    // ---- aggregate: lane = channel, fixed 16 iters (alpha=0 masks padding)
    #pragma unroll 4
    for (int j = 0; j < 16; j += 2) {
      acc0 = fmaf(readlane_f(alpha, j),     tw[j * 68 + lane],       acc0);
      acc1 = fmaf(readlane_f(alpha, j + 1), tw[(j + 1) * 68 + lane], acc1);
    }
  }

  float inv = 1.f / (d + 1e-16f);
  float out = (acc0 + acc1) * inv + bo[lane];
  xout[(size_t)n * 64 + lane] = fmaxf(out, 0.f);  // relu after every conv
}

__global__ void k_mean(const float* __restrict__ x, double* __restrict__ meanbuf, int nNodes) {
  __shared__ float sacc[256];
  int lane = threadIdx.x & 63;
  int wv = threadIdx.x >> 6;
  int gw = blockIdx.x * 4 + wv;
  int stride = gridDim.x * 4;
  float acc = 0.f;
  for (int n = gw; n < nNodes; n += stride) acc += x[(size_t)n * 64 + lane];
  sacc[threadIdx.x] = acc;
  __syncthreads();
  if (threadIdx.x < 64) {
    float a = sacc[threadIdx.x] + sacc[threadIdx.x + 64] + sacc[threadIdx.x + 128] + sacc[threadIdx.x + 192];
    atomicAdd(&meanbuf[lane], (double)a);
  }
}

__global__ void k_mlp(const double* __restrict__ meanbuf,
                      const float* __restrict__ Wm1, const float* __restrict__ bm1,
                      const float* __restrict__ Wm2, const float* __restrict__ bm2,
                      const float* __restrict__ Wm3, const float* __restrict__ bm3,
                      float* __restrict__ out, double invN) {
  __shared__ float xm[64];
  __shared__ float h1[32];
  __shared__ float h2[16];
  int t = threadIdx.x;
  xm[t] = (float)(meanbuf[t] * invN);
  __syncthreads();
  if (t < 32) {
    float a = bm1[t];
    for (int c = 0; c < 64; c++) a = fmaf(xm[c], Wm1[c * 32 + t], a);
    h1[t] = fmaxf(a, 0.f);
  }
  __syncthreads();
  if (t < 16) {
    float a = bm2[t];
    for (int c = 0; c < 32; c++) a = fmaf(h1[c], Wm2[c * 16 + t], a);
    h2[t] = fmaxf(a, 0.f);
  }
  __syncthreads();
  if (t == 0) {
    float a = bm3[0];
    for (int c = 0; c < 16; c++) a = fmaf(h2[c], Wm3[c], a);
    out[0] = a;
  }
}

extern "C" void kernel_launch(void* const* d_in, const int* in_sizes, int n_in,
                              void* d_out, int out_size, void* d_ws, size_t ws_size,
                              hipStream_t stream) {
  (void)n_in; (void)out_size; (void)ws_size;
  const int N = in_sizes[0] / 36;   // 50000
  const int E = in_sizes[1];        // 1600000

  const float* feat = (const float*)d_in[0];
  const float* eat  = (const float*)d_in[1];
  const int*   eidx = (const int*)d_in[2];
  const int* src = eidx;
  const int* dst = eidx + E;

  const float* L[4][7];  // Wl, bl, Wr, br, We, att, bo
  for (int l = 0; l < 4; l++)
    for (int j = 0; j < 7; j++) L[l][j] = (const float*)d_in[3 + l * 7 + j];
  const float* Wm1 = (const float*)d_in[31];
  const float* bm1 = (const float*)d_in[32];
  const float* Wm2 = (const float*)d_in[33];
  const float* bm2 = (const float*)d_in[34];
  const float* Wm3 = (const float*)d_in[35];
  const float* bm3 = (const float*)d_in[36];

  const int NBK = (N + 255) >> 8;  // buckets of 256 dst nodes (196)

  // workspace layout (512B aligned)
  char* ws = (char*)d_ws;
  size_t off = 0;
  auto alloc = [&](size_t bytes) {
    off = (off + 511) & ~(size_t)511;
    void* p = ws + off;
    off += bytes;
    return p;
  };
  int*    deg     = (int*)alloc((size_t)N * 4);
  int*    bcur    = (int*)alloc((size_t)NBK * 16 * 4);  // 1 counter per 64B line
  double* meanbuf = (double*)alloc(64 * 8);
  size_t zero_bytes = off;  // deg + bcur + meanbuf
  int*    rowptr  = (int*)alloc((size_t)(N + 1) * 4);
  int*    bsum    = (int*)alloc(64 * 4);
  int*    boffs   = (int*)alloc(64 * 4);
  int2*   pairs   = (int2*)alloc((size_t)E * 8);
  float*  xA      = (float*)alloc((size_t)N * 64 * 4);  // xl
  float*  xB      = (float*)alloc((size_t)N * 64 * 4);  // xr
  float*  xC      = (float*)alloc((size_t)N * 64 * 4);  // layer out / next in
  uint2*  tmp     = (uint2*)xC;  // aliases xC: dead until k_edge layer 1 writes it

  hipMemsetAsync(d_ws, 0, zero_bytes, stream);

  const int TILES = 4;          // 64 nodes per transform block
  int egrid = (E + 255) / 256;
  int sgrid = (E + 4095) / 4096; // k_scatter: 4096 edges per 256-thr block
  int tgrid = (N + 16 * TILES - 1) / (16 * TILES);
  int ngrid = (N + 3) / 4;       // k_edge: 4 nodes (waves) per 256-thr block
  int nb = (N + 1023) / 1024;    // scan blocks (49 <= 64)

  k_hist<<<egrid, 256, 0, stream>>>(dst, deg, E);
  k_scanA<<<nb, 256, 0, stream>>>(deg, bsum, N);
  k_scanB<<<1, 64, 0, stream>>>(bsum, boffs, rowptr, nb, N);
  k_scanC<<<nb, 256, 0, stream>>>(deg, boffs, rowptr, N);
  k_scatter<<<sgrid, 256, 0, stream>>>(src, dst, eat, rowptr, bcur, tmp, E, NBK);
  k_csr<<<NBK, 256, 0, stream>>>(rowptr, tmp, pairs, N);

  for (int l = 0; l < 4; l++) {
    if (l == 0)
      k_transform<36, TILES><<<tgrid, 256, 0, stream>>>(feat, L[0][0], L[0][1], L[0][2], L[0][3], xA, xB, N);
    else
      k_transform<64, TILES><<<tgrid, 256, 0, stream>>>(xC, L[l][0], L[l][1], L[l][2], L[l][3], xA, xB, N);
    k_edge<<<ngrid, 256, 0, stream>>>(xA, xB, rowptr, (const int*)pairs,
                                      L[l][4], L[l][5], L[l][6], xC, N);
  }

  k_mean<<<256, 256, 0, stream>>>(xC, meanbuf, N);
  k_mlp<<<1, 64, 0, stream>>>(meanbuf, Wm1, bm1, Wm2, bm2, Wm3, bm3, (float*)d_out, 1.0 / (double)N);
}

// Round 11
// 577.752 us; speedup vs baseline: 1.3025x; 1.0893x over previous
//
#include <hip/hip_runtime.h>

// ---------------------------------------------------------------------------
// GATv2 x4 + MLP readout.  R11 = R10 + spill-fixed register-direct k_edge.
//   k_edge: ZERO LDS.  Lane = (c4 = lane&15 channel-group, r = lane>>4).
//     Lane owns edges {4i+r} of each 16-edge chunk and channels [4c4,4c4+4).
//     Per chunk: 4 int2 pair loads (broadcast across same-r lanes), 4
//     coalesced float4 row gathers (16 lanes x 16B = full 256B row), score
//     partial dots + butterfly over c4 (offs 1..8), softmax folds over r
//     (offs 16,32), aggregate IN REGISTERS with zero alpha shuffles (the
//     consuming lane computed its own alphas).  __launch_bounds__(256,5):
//     R9 lesson — bounds(256,8) forced a 64-VGPR cap -> scratch spills
//     (+170MB HBM traffic); 102-reg ceiling removes them, LDS=0 keeps
//     occupancy compiler-determined.
//   k_transform: weights staged once per block, 4 tiles x 16 nodes (R10).
// CSR build: hist -> scanA/B/C -> k_scatter (LDS-binned, spread atomics;
//   R5 lesson: per-edge atomics on few lines serialize) -> k_csr.
// Readout: f64-atomic mean + 1-block MLP.   N <= 65536 packing assumption.
// R7 lesson: per-lane-gather lds-DMA explodes HBM; plain VMEM gathers with
//   full-row lane coverage stay L2-friendly.
// ---------------------------------------------------------------------------

__device__ __forceinline__ float readlane_f(float v, int l) {
  return __int_as_float(__builtin_amdgcn_readlane(__float_as_int(v), l));
}
__device__ __forceinline__ int rfl(int v) { return __builtin_amdgcn_readfirstlane(v); }

__device__ __forceinline__ void row_to_lds(const float* g, float* l) {
  __builtin_amdgcn_global_load_lds((const __attribute__((address_space(1))) void*)g,
                                   (__attribute__((address_space(3))) void*)l,
                                   4, 0, 0);
}

__global__ void k_hist(const int* __restrict__ dst, int* __restrict__ deg, int E) {
  int e = blockIdx.x * blockDim.x + threadIdx.x;
  if (e < E) atomicAdd(&deg[dst[e]], 1);
}

// ---- parallel exclusive scan over n ints: A (block sums), B (scan sums), C
__global__ void __launch_bounds__(256) k_scanA(const int* __restrict__ deg,
                                               int* __restrict__ bsum, int n) {
  __shared__ int ws[4];
  int tid = threadIdx.x, lane = tid & 63, wv = tid >> 6;
  int base = blockIdx.x * 1024 + tid;
  int s = 0;
  #pragma unroll
  for (int k = 0; k < 4; k++) {
    int i = base + k * 256;
    if (i < n) s += deg[i];
  }
  #pragma unroll
  for (int o = 32; o > 0; o >>= 1) s += __shfl_xor(s, o, 64);
  if (lane == 0) ws[wv] = s;
  __syncthreads();
  if (tid == 0) bsum[blockIdx.x] = ws[0] + ws[1] + ws[2] + ws[3];
}

__global__ void k_scanB(const int* __restrict__ bsum, int* __restrict__ boffs,
                        int* __restrict__ rowptr, int nb, int n) {
  int lane = threadIdx.x;  // 64 threads, nb <= 64
  int v = (lane < nb) ? bsum[lane] : 0;
  int x = v;
  #pragma unroll
  for (int o = 1; o < 64; o <<= 1) {
    int t = __shfl_up(x, o, 64);
    if (lane >= o) x += t;
  }
  if (lane < nb) boffs[lane] = x - v;
  if (lane == 63) rowptr[n] = x;
}

__global__ void __launch_bounds__(256) k_scanC(const int* __restrict__ deg,
                                               const int* __restrict__ boffs,
                                               int* __restrict__ rowptr, int n) {
  __shared__ int wtot[4];
  int tid = threadIdx.x, lane = tid & 63, wv = tid >> 6;
  int i0 = blockIdx.x * 1024 + tid * 4;
  int4 v = make_int4(0, 0, 0, 0);
  if (i0 + 3 < n) v = *(const int4*)(deg + i0);
  else {
    if (i0 + 0 < n) v.x = deg[i0 + 0];
    if (i0 + 1 < n) v.y = deg[i0 + 1];
    if (i0 + 2 < n) v.z = deg[i0 + 2];
  }
  int s = v.x + v.y + v.z + v.w;
  int x = s;
  #pragma unroll
  for (int o = 1; o < 64; o <<= 1) {
    int t = __shfl_up(x, o, 64);
    if (lane >= o) x += t;
  }
  if (lane == 63) wtot[wv] = x;
  __syncthreads();
  int wexcl = 0;
  for (int k = 0; k < 4; k++) if (k < wv) wexcl += wtot[k];
  int excl = boffs[blockIdx.x] + wexcl + (x - s);
  int4 o4;
  o4.x = excl; o4.y = o4.x + v.x; o4.z = o4.y + v.y; o4.w = o4.z + v.z;
  if (i0 + 3 < n) *(int4*)(rowptr + i0) = o4;
  else {
    if (i0 + 0 < n) rowptr[i0 + 0] = o4.x;
    if (i0 + 1 < n) rowptr[i0 + 1] = o4.y;
    if (i0 + 2 < n) rowptr[i0 + 2] = o4.z;
  }
}

// ---- pass 1: block-binned scatter into bucket regions (256 dst per bucket)
#define NBK_MAX 256
__global__ void __launch_bounds__(256) k_scatter(
    const int* __restrict__ src, const int* __restrict__ dst,
    const float* __restrict__ ea_in, const int* __restrict__ rowptr,
    int* __restrict__ bcur, uint2* __restrict__ tmp, int E, int nbk) {
  __shared__ int cnt[NBK_MAX];
  __shared__ int cur[NBK_MAX];
  __shared__ int gbase[NBK_MAX];
  __shared__ int sbase[NBK_MAX];
  int tid = threadIdx.x;
  if (tid < nbk) {
    cnt[tid] = 0;
    cur[tid] = 0;
    sbase[tid] = rowptr[tid << 8];
  }
  __syncthreads();
  int base = blockIdx.x * 4096 + tid;
  uint2 rec[16];
  #pragma unroll
  for (int k = 0; k < 16; k++) {
    int e = base + k * 256;
    if (e < E) {
      unsigned d = (unsigned)dst[e];
      rec[k] = make_uint2((d << 16) | (unsigned)src[e],
                          (unsigned)__float_as_int(ea_in[e]));
      atomicAdd(&cnt[d >> 8], 1);
    } else {
      rec[k] = make_uint2(0u, 0u);
    }
  }
  __syncthreads();
  if (tid < nbk) {
    int c = cnt[tid];
    gbase[tid] = (c > 0) ? atomicAdd(&bcur[tid * 16], c) : 0;
  }
  __syncthreads();
  #pragma unroll
  for (int k = 0; k < 16; k++) {
    int e = base + k * 256;
    if (e < E) {
      int b = (int)(rec[k].x >> 24);
      int slot = atomicAdd(&cur[b], 1);
      tmp[sbase[b] + gbase[b] + slot] = rec[k];
    }
  }
}

// ---- pass 2: one block per bucket; LDS cursors; L2-resident final scatter
__global__ void __launch_bounds__(256) k_csr(const int* __restrict__ rowptr,
                                             const uint2* __restrict__ tmp,
                                             int2* __restrict__ pairs, int N) {
  __shared__ int sRP[257];
  __shared__ int cur[256];
  int b = blockIdx.x;
  int n0 = b << 8;
  int tid = threadIdx.x;
  sRP[tid] = rowptr[min(n0 + tid, N)];
  if (tid == 0) sRP[256] = rowptr[min(n0 + 256, N)];
  cur[tid] = 0;
  __syncthreads();
  int lo = sRP[0], hi = sRP[256];
  for (int k = lo + tid; k < hi; k += 256) {
    uint2 rec = tmp[k];
    int local = (int)(rec.x >> 16) - n0;
    int pos = sRP[local] + atomicAdd(&cur[local], 1);
    pairs[pos] = make_int2((int)(rec.x & 0xffffu), (int)rec.y);
  }
}

// xl = x @ Wl + bl ; xr = x @ Wr + br.  Weights staged once per block,
// reused across TILES tiles of 16 nodes (R10).
template <int DIN, int TILES>
__global__ void __launch_bounds__(256) k_transform(
    const float* __restrict__ x, const float* __restrict__ Wl, const float* __restrict__ bl,
    const float* __restrict__ Wr, const float* __restrict__ br,
    float* __restrict__ xl, float* __restrict__ xr, int nNodes) {
  __shared__ __align__(16) float sWl[DIN * 64];
  __shared__ __align__(16) float sWr[DIN * 64];
  __shared__ float sx[16][DIN + 1];
  int tid = threadIdx.x;
  for (int i = tid; i < DIN * 64; i += 256) { sWl[i] = Wl[i]; sWr[i] = Wr[i]; }
  int node = tid >> 4;          // 0..15
  int t4 = (tid & 15) * 4;      // col group
  float4 bl4 = *(const float4*)(bl + t4);
  float4 br4 = *(const float4*)(br + t4);
  for (int t = 0; t < TILES; t++) {
    int nb = (blockIdx.x * TILES + t) * 16;
    if (nb >= nNodes) break;    // uniform across block
    __syncthreads();            // weights ready / previous tile consumed
    for (int i = tid; i < 16 * DIN; i += 256) {
      int ln = i / DIN, c = i % DIN;
      int g = nb + ln;
      sx[ln][c] = (g < nNodes) ? x[(size_t)g * DIN + c] : 0.f;
    }
    __syncthreads();
    float4 accl = bl4;
    float4 accr = br4;
    const float* xrow = sx[node];
    #pragma unroll 4
    for (int k = 0; k < DIN; k++) {
      float xv = xrow[k];
      float4 wl = *(const float4*)(sWl + k * 64 + t4);
      float4 wr = *(const float4*)(sWr + k * 64 + t4);
      accl.x = fmaf(xv, wl.x, accl.x); accl.y = fmaf(xv, wl.y, accl.y);
      accl.z = fmaf(xv, wl.z, accl.z); accl.w = fmaf(xv, wl.w, accl.w);
      accr.x = fmaf(xv, wr.x, accr.x); accr.y = fmaf(xv, wr.y, accr.y);
      accr.z = fmaf(xv, wr.z, accr.z); accr.w = fmaf(xv, wr.w, accr.w);
    }
    int g = nb + node;
    if (g < nNodes) {
      *(float4*)(xl + (size_t)g * 64 + t4) = accl;
      *(float4*)(xr + (size_t)g * 64 + t4) = accr;
    }
  }
}

// Fused score + online softmax + aggregate.  One wave per node, chunk = 16,
// zero LDS, register aggregate with zero alpha shuffles.
#define SC1(T, EA, OUT) { float u, acc; \
  u = T.x + fmaf(EA, We4.x, xr4.x); u = fmaxf(u, 0.2f * u); acc = at4.x * u; \
  u = T.y + fmaf(EA, We4.y, xr4.y); u = fmaxf(u, 0.2f * u); acc = fmaf(at4.y, u, acc); \
  u = T.z + fmaf(EA, We4.z, xr4.z); u = fmaxf(u, 0.2f * u); acc = fmaf(at4.z, u, acc); \
  u = T.w + fmaf(EA, We4.w, xr4.w); u = fmaxf(u, 0.2f * u); acc = fmaf(at4.w, u, acc); \
  OUT = acc; }

__global__ void __launch_bounds__(256, 5) k_edge(
    const float* __restrict__ xl, const float* __restrict__ xr,
    const int* __restrict__ rowptr, const int2* __restrict__ pairs,
    const float* __restrict__ We, const float* __restrict__ att,
    const float* __restrict__ bo, float* __restrict__ xout, int nNodes) {
  int lane = threadIdx.x & 63;
  int wv = rfl((int)(threadIdx.x >> 6));
  int n = rfl(blockIdx.x * 4 + wv);
  if (n >= nNodes) return;
  int c4 = lane & 15;   // channel group
  int r  = lane >> 4;   // edge subgroup (0..3); lane owns edges {4i+r}
  int cb = c4 * 4;      // first channel

  float4 We4 = *(const float4*)(We + cb);
  float4 at4 = *(const float4*)(att + cb);
  float4 xr4 = *(const float4*)(xr + (size_t)n * 64 + cb);
  int s0 = rfl(rowptr[n]);
  int s1 = rfl(rowptr[n + 1]);
  int last = s1 - 1;

  float m = -3.0e38f, d = 0.f;
  float4 A = {0.f, 0.f, 0.f, 0.f};

  for (int kb = s0; kb < s1; kb += 16) {
    int cnt = rfl(min(16, s1 - kb));
    // each lane loads its own 4 edge records (same-r lanes broadcast)
    int2 p0 = pairs[min(kb + r,      last)];
    int2 p1 = pairs[min(kb + 4 + r,  last)];
    int2 p2 = pairs[min(kb + 8 + r,  last)];
    int2 p3 = pairs[min(kb + 12 + r, last)];
    float ea0 = __int_as_float(p0.y);
    float ea1 = __int_as_float(p1.y);
    float ea2 = __int_as_float(p2.y);
    float ea3 = __int_as_float(p3.y);

    // coalesced row gathers: 16 same-r lanes cover the full 256B row
    float4 t0 = *(const float4*)(xl + (size_t)(unsigned)p0.x * 64 + cb);
    float4 t1 = *(const float4*)(xl + (size_t)(unsigned)p1.x * 64 + cb);
    float4 t2 = *(const float4*)(xl + (size_t)(unsigned)p2.x * 64 + cb);
    float4 t3 = *(const float4*)(xl + (size_t)(unsigned)p3.x * 64 + cb);

    // per-lane 4-channel partial dots
    float sc0, sc1, sc2, sc3;
    SC1(t0, ea0, sc0)
    SC1(t1, ea1, sc1)
    SC1(t2, ea2, sc2)
    SC1(t3, ea3, sc3)

    // complete the dots: butterfly over the 16 c4-lanes
    #pragma unroll
    for (int o = 1; o <= 8; o <<= 1) {
      sc0 += __shfl_xor(sc0, o, 64);
      sc1 += __shfl_xor(sc1, o, 64);
      sc2 += __shfl_xor(sc2, o, 64);
      sc3 += __shfl_xor(sc3, o, 64);
    }
    // mask padded edges (4i + r >= cnt) -> alpha = 0
    sc0 = (r < cnt)      ? sc0 : -3.0e38f;
    sc1 = (4 + r < cnt)  ? sc1 : -3.0e38f;
    sc2 = (8 + r < cnt)  ? sc2 : -3.0e38f;
    sc3 = (12 + r < cnt) ? sc3 : -3.0e38f;

    // online softmax (cross-lane only over r: offsets 16, 32)
    float mc = fmaxf(fmaxf(sc0, sc1), fmaxf(sc2, sc3));
    mc = fmaxf(mc, __shfl_xor(mc, 16, 64));
    mc = fmaxf(mc, __shfl_xor(mc, 32, 64));
    float newm = fmaxf(m, mc);
    float rf = __expf(m - newm);     // 0 on first chunk, 1 if max unchanged
    float a0 = __expf(sc0 - newm);
    float a1 = __expf(sc1 - newm);
    float a2 = __expf(sc2 - newm);
    float a3 = __expf(sc3 - newm);
    float ds = (a0 + a1) + (a2 + a3);
    ds += __shfl_xor(ds, 16, 64);
    ds += __shfl_xor(ds, 32, 64);
    d = d * rf + ds;
    m = newm;

    // aggregate in registers: this lane computed its own alphas
    A.x = fmaf(a0, t0.x, A.x * rf); A.y = fmaf(a0, t0.y, A.y * rf);
    A.z = fmaf(a0, t0.z, A.z * rf); A.w = fmaf(a0, t0.w, A.w * rf);
    A.x = fmaf(a1, t1.x, A.x); A.y = fmaf(a1, t1.y, A.y);
    A.z = fmaf(a1, t1.z, A.z); A.w = fmaf(a1, t1.w, A.w);
    A.x = fmaf(a2, t2.x, A.x); A.y = fmaf(a2, t2.y, A.y);
    A.z = fmaf(a2, t2.z, A.z); A.w = fmaf(a2, t2.w, A.w);
    A.x = fmaf(a3, t3.x, A.x); A.y = fmaf(a3, t3.y, A.y);
    A.z = fmaf(a3, t3.z, A.z); A.w = fmaf(a3, t3.w, A.w);
  }

  // combine the 4 r-subgroups (8 shuffles per node)
  A.x += __shfl_xor(A.x, 16, 64); A.y += __shfl_xor(A.y, 16, 64);
  A.z += __shfl_xor(A.z, 16, 64); A.w += __shfl_xor(A.w, 16, 64);
  A.x += __shfl_xor(A.x, 32, 64); A.y += __shfl_xor(A.y, 32, 64);
  A.z += __shfl_xor(A.z, 32, 64); A.w += __shfl_xor(A.w, 32, 64);

  float inv = 1.f / (d + 1e-16f);
  if (r == 0) {  // 16 lanes, contiguous 256B -> fully coalesced store
    float4 bo4 = *(const float4*)(bo + cb);
    float4 o4;
    o4.x = fmaxf(fmaf(A.x, inv, bo4.x), 0.f);
    o4.y = fmaxf(fmaf(A.y, inv, bo4.y), 0.f);
    o4.z = fmaxf(fmaf(A.z, inv, bo4.z), 0.f);
    o4.w = fmaxf(fmaf(A.w, inv, bo4.w), 0.f);
    *(float4*)(xout + (size_t)n * 64 + cb) = o4;
  }
}

__global__ void k_mean(const float* __restrict__ x, double* __restrict__ meanbuf, int nNodes) {
  __shared__ float sacc[256];
  int lane = threadIdx.x & 63;
  int wv = threadIdx.x >> 6;
  int gw = blockIdx.x * 4 + wv;
  int stride = gridDim.x * 4;
  float acc = 0.f;
  for (int n = gw; n < nNodes; n += stride) acc += x[(size_t)n * 64 + lane];
  sacc[threadIdx.x] = acc;
  __syncthreads();
  if (threadIdx.x < 64) {
    float a = sacc[threadIdx.x] + sacc[threadIdx.x + 64] + sacc[threadIdx.x + 128] + sacc[threadIdx.x + 192];
    atomicAdd(&meanbuf[lane], (double)a);
  }
}

__global__ void k_mlp(const double* __restrict__ meanbuf,
                      const float* __restrict__ Wm1, const float* __restrict__ bm1,
                      const float* __restrict__ Wm2, const float* __restrict__ bm2,
                      const float* __restrict__ Wm3, const float* __restrict__ bm3,
                      float* __restrict__ out, double invN) {
  __shared__ float xm[64];
  __shared__ float h1[32];
  __shared__ float h2[16];
  int t = threadIdx.x;
  xm[t] = (float)(meanbuf[t] * invN);
  __syncthreads();
  if (t < 32) {
    float a = bm1[t];
    for (int c = 0; c < 64; c++) a = fmaf(xm[c], Wm1[c * 32 + t], a);
    h1[t] = fmaxf(a, 0.f);
  }
  __syncthreads();
  if (t < 16) {
    float a = bm2[t];
    for (int c = 0; c < 32; c++) a = fmaf(h1[c], Wm2[c * 16 + t], a);
    h2[t] = fmaxf(a, 0.f);
  }
  __syncthreads();
  if (t == 0) {
    float a = bm3[0];
    for (int c = 0; c < 16; c++) a = fmaf(h2[c], Wm3[c], a);
    out[0] = a;
  }
}

extern "C" void kernel_launch(void* const* d_in, const int* in_sizes, int n_in,
                              void* d_out, int out_size, void* d_ws, size_t ws_size,
                              hipStream_t stream) {
  (void)n_in; (void)out_size; (void)ws_size;
  const int N = in_sizes[0] / 36;   // 50000
  const int E = in_sizes[1];        // 1600000

  const float* feat = (const float*)d_in[0];
  const float* eat  = (const float*)d_in[1];
  const int*   eidx = (const int*)d_in[2];
  const int* src = eidx;
  const int* dst = eidx + E;

  const float* L[4][7];  // Wl, bl, Wr, br, We, att, bo
  for (int l = 0; l < 4; l++)
    for (int j = 0; j < 7; j++) L[l][j] = (const float*)d_in[3 + l * 7 + j];
  const float* Wm1 = (const float*)d_in[31];
  const float* bm1 = (const float*)d_in[32];
  const float* Wm2 = (const float*)d_in[33];
  const float* bm2 = (const float*)d_in[34];
  const float* Wm3 = (const float*)d_in[35];
  const float* bm3 = (const float*)d_in[36];

  const int NBK = (N + 255) >> 8;  // buckets of 256 dst nodes (196)

  // workspace layout (512B aligned)
  char* ws = (char*)d_ws;
  size_t off = 0;
  auto alloc = [&](size_t bytes) {
    off = (off + 511) & ~(size_t)511;
    void* p = ws + off;
    off += bytes;
    return p;
  };
  int*    deg     = (int*)alloc((size_t)N * 4);
  int*    bcur    = (int*)alloc((size_t)NBK * 16 * 4);  // 1 counter per 64B line
  double* meanbuf = (double*)alloc(64 * 8);
  size_t zero_bytes = off;  // deg + bcur + meanbuf
  int*    rowptr  = (int*)alloc((size_t)(N + 1) * 4);
  int*    bsum    = (int*)alloc(64 * 4);
  int*    boffs   = (int*)alloc(64 * 4);
  int2*   pairs   = (int2*)alloc((size_t)E * 8);
  float*  xA      = (float*)alloc((size_t)N * 64 * 4);  // xl
  float*  xB      = (float*)alloc((size_t)N * 64 * 4);  // xr
  float*  xC      = (float*)alloc((size_t)N * 64 * 4);  // layer out / next in
  uint2*  tmp     = (uint2*)xC;  // aliases xC: dead until k_edge layer 1 writes it

  hipMemsetAsync(d_ws, 0, zero_bytes, stream);

  const int TILES = 4;          // 64 nodes per transform block
  int egrid = (E + 255) / 256;
  int sgrid = (E + 4095) / 4096; // k_scatter: 4096 edges per 256-thr block
  int tgrid = (N + 16 * TILES - 1) / (16 * TILES);
  int ngrid = (N + 3) / 4;       // k_edge: 4 nodes (waves) per 256-thr block
  int nb = (N + 1023) / 1024;    // scan blocks (49 <= 64)

  k_hist<<<egrid, 256, 0, stream>>>(dst, deg, E);
  k_scanA<<<nb, 256, 0, stream>>>(deg, bsum, N);
  k_scanB<<<1, 64, 0, stream>>>(bsum, boffs, rowptr, nb, N);
  k_scanC<<<nb, 256, 0, stream>>>(deg, boffs, rowptr, N);
  k_scatter<<<sgrid, 256, 0, stream>>>(src, dst, eat, rowptr, bcur, tmp, E, NBK);
  k_csr<<<NBK, 256, 0, stream>>>(rowptr, tmp, pairs, N);

  for (int l = 0; l < 4; l++) {
    if (l == 0)
      k_transform<36, TILES><<<tgrid, 256, 0, stream>>>(feat, L[0][0], L[0][1], L[0][2], L[0][3], xA, xB, N);
    else
      k_transform<64, TILES><<<tgrid, 256, 0, stream>>>(xC, L[l][0], L[l][1], L[l][2], L[l][3], xA, xB, N);
    k_edge<<<ngrid, 256, 0, stream>>>(xA, xB, rowptr, pairs,
                                      L[l][4], L[l][5], L[l][6], xC, N);
  }

  k_mean<<<256, 256, 0, stream>>>(xC, meanbuf, N);
  k_mlp<<<1, 64, 0, stream>>>(meanbuf, Wm1, bm1, Wm2, bm2, Wm3, bm3, (float*)d_out, 1.0 / (double)N);
}

// Round 12
// 519.516 us; speedup vs baseline: 1.4485x; 1.1121x over previous
//
#include <hip/hip_runtime.h>

// ---------------------------------------------------------------------------
// GATv2 x4 + MLP readout.  R12 = R11 with the per-node histogram DELETED.
//   CSR build (no k_hist, no deg scan):
//     k_bcount: per-block LDS histogram over 196 BUCKETS (256 dst each) ->
//       <=196 padded global atomics/block (R5/R11 lesson: 1.6M per-node
//       atomics cost 70us at 0.4% VALU; bucket counters 1/line are free).
//     k_bscan: 1 block scans 196 bucket counts -> boffs.
//     k_scatter: LDS-binned scatter of packed (dst16|src16,ea) records into
//       bucket regions (~77k spread atomics).
//     k_csr: per bucket: pass1 LDS per-node histogram + scan -> writes
//       rowptr[n0..n0+255] directly; pass2 scatters records to final CSR
//       positions (records L2-hot between passes).
//   k_edge (R11-proven, spill-free): ZERO LDS, lane=(c4,r), per-lane edge
//     records, coalesced quarter-wave row gathers, register aggregate with
//     zero alpha shuffles, __launch_bounds__(256,5) (R9 lesson: a 64-VGPR
//     cap forces scratch spills, +170MB HBM).
//   k_transform: weights staged once per block, 4 tiles x 16 nodes.
// Readout: f64-atomic mean + 1-block MLP.   N <= 65536 packing assumption.
// R7 lesson: per-lane-gather lds-DMA explodes HBM; plain VMEM gathers with
//   full-row lane coverage stay L2-friendly.
// ---------------------------------------------------------------------------

__device__ __forceinline__ int rfl(int v) { return __builtin_amdgcn_readfirstlane(v); }

#define NBK_MAX 256

// ---- bucket-level histogram: LDS per block, padded global counters
__global__ void __launch_bounds__(256) k_bcount(const int* __restrict__ dst,
                                                int* __restrict__ bkcnt, int E, int nbk) {
  __shared__ int cnt[NBK_MAX];
  int tid = threadIdx.x;
  if (tid < nbk) cnt[tid] = 0;
  __syncthreads();
  int base = blockIdx.x * 4096 + tid;
  #pragma unroll
  for (int k = 0; k < 16; k++) {
    int e = base + k * 256;
    if (e < E) atomicAdd(&cnt[((unsigned)dst[e]) >> 8], 1);
  }
  __syncthreads();
  if (tid < nbk) {
    int c = cnt[tid];
    if (c > 0) atomicAdd(&bkcnt[tid * 16], c);  // 1 counter per 64B line
  }
}

// ---- scan 196 bucket counts -> boffs[0..nbk]
__global__ void k_bscan(const int* __restrict__ bkcnt, int* __restrict__ boffs,
                        int nbk, int E) {
  __shared__ int wsum[4];
  int tid = threadIdx.x, lane = tid & 63, wv = tid >> 6;
  int v = (tid < nbk) ? bkcnt[tid * 16] : 0;
  int x = v;
  #pragma unroll
  for (int o = 1; o < 64; o <<= 1) {
    int t = __shfl_up(x, o, 64);
    if (lane >= o) x += t;
  }
  if (lane == 63) wsum[wv] = x;
  __syncthreads();
  int wo = 0;
  for (int k = 0; k < 4; k++) if (k < wv) wo += wsum[k];
  if (tid < nbk) boffs[tid] = wo + (x - v);
  if (tid == 0) boffs[nbk] = E;
}

// ---- pass 1: block-binned scatter into bucket regions (256 dst per bucket)
__global__ void __launch_bounds__(256) k_scatter(
    const int* __restrict__ src, const int* __restrict__ dst,
    const float* __restrict__ ea_in, const int* __restrict__ boffs,
    int* __restrict__ bcur, uint2* __restrict__ tmp, int E, int nbk) {
  __shared__ int cnt[NBK_MAX];
  __shared__ int cur[NBK_MAX];
  __shared__ int gbase[NBK_MAX];
  __shared__ int sbase[NBK_MAX];
  int tid = threadIdx.x;
  if (tid < nbk) {
    cnt[tid] = 0;
    cur[tid] = 0;
    sbase[tid] = boffs[tid];
  }
  __syncthreads();
  int base = blockIdx.x * 4096 + tid;
  uint2 rec[16];
  #pragma unroll
  for (int k = 0; k < 16; k++) {
    int e = base + k * 256;
    if (e < E) {
      unsigned d = (unsigned)dst[e];
      rec[k] = make_uint2((d << 16) | (unsigned)src[e],
                          (unsigned)__float_as_int(ea_in[e]));
      atomicAdd(&cnt[d >> 8], 1);
    } else {
      rec[k] = make_uint2(0u, 0u);
    }
  }
  __syncthreads();
  if (tid < nbk) {
    int c = cnt[tid];
    gbase[tid] = (c > 0) ? atomicAdd(&bcur[tid * 16], c) : 0;
  }
  __syncthreads();
  #pragma unroll
  for (int k = 0; k < 16; k++) {
    int e = base + k * 256;
    if (e < E) {
      int b = (int)(rec[k].x >> 24);
      int slot = atomicAdd(&cur[b], 1);
      tmp[sbase[b] + gbase[b] + slot] = rec[k];
    }
  }
}

// ---- pass 2: per bucket: LDS node-histogram + scan -> rowptr; then scatter
__global__ void __launch_bounds__(256) k_csr(const int* __restrict__ boffs,
                                             const uint2* __restrict__ tmp,
                                             int2* __restrict__ pairs,
                                             int* __restrict__ rowptr, int N) {
  __shared__ int cnt[256];
  __shared__ int pref[256];
  __shared__ int cur[256];
  __shared__ int wsum[4];
  int b = blockIdx.x;
  int n0 = b << 8;
  int tid = threadIdx.x, lane = tid & 63, wv = tid >> 6;
  cnt[tid] = 0;
  cur[tid] = 0;
  __syncthreads();
  int lo = boffs[b], hi = boffs[b + 1];
  for (int k = lo + tid; k < hi; k += 256)
    atomicAdd(&cnt[(int)(tmp[k].x >> 16) - n0], 1);
  __syncthreads();
  int v = cnt[tid];
  int x = v;
  #pragma unroll
  for (int o = 1; o < 64; o <<= 1) {
    int t = __shfl_up(x, o, 64);
    if (lane >= o) x += t;
  }
  if (lane == 63) wsum[wv] = x;
  __syncthreads();
  int wo = 0;
  for (int k = 0; k < 4; k++) if (k < wv) wo += wsum[k];
  int start = lo + wo + (x - v);   // exclusive prefix -> global CSR start
  pref[tid] = start;
  int nn = n0 + tid;
  if (nn <= N) rowptr[nn] = start; // last bucket's boundary lane writes rowptr[N]=E
  __syncthreads();
  for (int k = lo + tid; k < hi; k += 256) {
    uint2 rec = tmp[k];
    int local = (int)(rec.x >> 16) - n0;
    int pos = pref[local] + atomicAdd(&cur[local], 1);
    pairs[pos] = make_int2((int)(rec.x & 0xffffu), (int)rec.y);
  }
}

// xl = x @ Wl + bl ; xr = x @ Wr + br.  Weights staged once per block,
// reused across TILES tiles of 16 nodes.
template <int DIN, int TILES>
__global__ void __launch_bounds__(256) k_transform(
    const float* __restrict__ x, const float* __restrict__ Wl, const float* __restrict__ bl,
    const float* __restrict__ Wr, const float* __restrict__ br,
    float* __restrict__ xl, float* __restrict__ xr, int nNodes) {
  __shared__ __align__(16) float sWl[DIN * 64];
  __shared__ __align__(16) float sWr[DIN * 64];
  __shared__ float sx[16][DIN + 1];
  int tid = threadIdx.x;
  for (int i = tid; i < DIN * 64; i += 256) { sWl[i] = Wl[i]; sWr[i] = Wr[i]; }
  int node = tid >> 4;          // 0..15
  int t4 = (tid & 15) * 4;      // col group
  float4 bl4 = *(const float4*)(bl + t4);
  float4 br4 = *(const float4*)(br + t4);
  for (int t = 0; t < TILES; t++) {
    int nb = (blockIdx.x * TILES + t) * 16;
    if (nb >= nNodes) break;    // uniform across block
    __syncthreads();            // weights ready / previous tile consumed
    for (int i = tid; i < 16 * DIN; i += 256) {
      int ln = i / DIN, c = i % DIN;
      int g = nb + ln;
      sx[ln][c] = (g < nNodes) ? x[(size_t)g * DIN + c] : 0.f;
    }
    __syncthreads();
    float4 accl = bl4;
    float4 accr = br4;
    const float* xrow = sx[node];
    #pragma unroll 4
    for (int k = 0; k < DIN; k++) {
      float xv = xrow[k];
      float4 wl = *(const float4*)(sWl + k * 64 + t4);
      float4 wr = *(const float4*)(sWr + k * 64 + t4);
      accl.x = fmaf(xv, wl.x, accl.x); accl.y = fmaf(xv, wl.y, accl.y);
      accl.z = fmaf(xv, wl.z, accl.z); accl.w = fmaf(xv, wl.w, accl.w);
      accr.x = fmaf(xv, wr.x, accr.x); accr.y = fmaf(xv, wr.y, accr.y);
      accr.z = fmaf(xv, wr.z, accr.z); accr.w = fmaf(xv, wr.w, accr.w);
    }
    int g = nb + node;
    if (g < nNodes) {
      *(float4*)(xl + (size_t)g * 64 + t4) = accl;
      *(float4*)(xr + (size_t)g * 64 + t4) = accr;
    }
  }
}

// Fused score + online softmax + aggregate.  One wave per node, chunk = 16,
// zero LDS, register aggregate with zero alpha shuffles.  (R11-proven.)
#define SC1(T, EA, OUT) { float u, acc; \
  u = T.x + fmaf(EA, We4.x, xr4.x); u = fmaxf(u, 0.2f * u); acc = at4.x * u; \
  u = T.y + fmaf(EA, We4.y, xr4.y); u = fmaxf(u, 0.2f * u); acc = fmaf(at4.y, u, acc); \
  u = T.z + fmaf(EA, We4.z, xr4.z); u = fmaxf(u, 0.2f * u); acc = fmaf(at4.z, u, acc); \
  u = T.w + fmaf(EA, We4.w, xr4.w); u = fmaxf(u, 0.2f * u); acc = fmaf(at4.w, u, acc); \
  OUT = acc; }

__global__ void __launch_bounds__(256, 5) k_edge(
    const float* __restrict__ xl, const float* __restrict__ xr,
    const int* __restrict__ rowptr, const int2* __restrict__ pairs,
    const float* __restrict__ We, const float* __restrict__ att,
    const float* __restrict__ bo, float* __restrict__ xout, int nNodes) {
  int lane = threadIdx.x & 63;
  int wv = rfl((int)(threadIdx.x >> 6));
  int n = rfl(blockIdx.x * 4 + wv);
  if (n >= nNodes) return;
  int c4 = lane & 15;   // channel group
  int r  = lane >> 4;   // edge subgroup (0..3); lane owns edges {4i+r}
  int cb = c4 * 4;      // first channel

  float4 We4 = *(const float4*)(We + cb);
  float4 at4 = *(const float4*)(att + cb);
  float4 xr4 = *(const float4*)(xr + (size_t)n * 64 + cb);
  int s0 = rfl(rowptr[n]);
  int s1 = rfl(rowptr[n + 1]);
  int last = s1 - 1;

  float m = -3.0e38f, d = 0.f;
  float4 A = {0.f, 0.f, 0.f, 0.f};

  for (int kb = s0; kb < s1; kb += 16) {
    int cnt = rfl(min(16, s1 - kb));
    // each lane loads its own 4 edge records (same-r lanes broadcast)
    int2 p0 = pairs[min(kb + r,      last)];
    int2 p1 = pairs[min(kb + 4 + r,  last)];
    int2 p2 = pairs[min(kb + 8 + r,  last)];
    int2 p3 = pairs[min(kb + 12 + r, last)];
    float ea0 = __int_as_float(p0.y);
    float ea1 = __int_as_float(p1.y);
    float ea2 = __int_as_float(p2.y);
    float ea3 = __int_as_float(p3.y);

    // coalesced row gathers: 16 same-r lanes cover the full 256B row
    float4 t0 = *(const float4*)(xl + (size_t)(unsigned)p0.x * 64 + cb);
    float4 t1 = *(const float4*)(xl + (size_t)(unsigned)p1.x * 64 + cb);
    float4 t2 = *(const float4*)(xl + (size_t)(unsigned)p2.x * 64 + cb);
    float4 t3 = *(const float4*)(xl + (size_t)(unsigned)p3.x * 64 + cb);

    // per-lane 4-channel partial dots
    float sc0, sc1, sc2, sc3;
    SC1(t0, ea0, sc0)
    SC1(t1, ea1, sc1)
    SC1(t2, ea2, sc2)
    SC1(t3, ea3, sc3)

    // complete the dots: butterfly over the 16 c4-lanes
    #pragma unroll
    for (int o = 1; o <= 8; o <<= 1) {
      sc0 += __shfl_xor(sc0, o, 64);
      sc1 += __shfl_xor(sc1, o, 64);
      sc2 += __shfl_xor(sc2, o, 64);
      sc3 += __shfl_xor(sc3, o, 64);
    }
    // mask padded edges (4i + r >= cnt) -> alpha = 0
    sc0 = (r < cnt)      ? sc0 : -3.0e38f;
    sc1 = (4 + r < cnt)  ? sc1 : -3.0e38f;
    sc2 = (8 + r < cnt)  ? sc2 : -3.0e38f;
    sc3 = (12 + r < cnt) ? sc3 : -3.0e38f;

    // online softmax (cross-lane only over r: offsets 16, 32)
    float mc = fmaxf(fmaxf(sc0, sc1), fmaxf(sc2, sc3));
    mc = fmaxf(mc, __shfl_xor(mc, 16, 64));
    mc = fmaxf(mc, __shfl_xor(mc, 32, 64));
    float newm = fmaxf(m, mc);
    float rf = __expf(m - newm);     // 0 on first chunk, 1 if max unchanged
    float a0 = __expf(sc0 - newm);
    float a1 = __expf(sc1 - newm);
    float a2 = __expf(sc2 - newm);
    float a3 = __expf(sc3 - newm);
    float ds = (a0 + a1) + (a2 + a3);
    ds += __shfl_xor(ds, 16, 64);
    ds += __shfl_xor(ds, 32, 64);
    d = d * rf + ds;
    m = newm;

    // aggregate in registers: this lane computed its own alphas
    A.x = fmaf(a0, t0.x, A.x * rf); A.y = fmaf(a0, t0.y, A.y * rf);
    A.z = fmaf(a0, t0.z, A.z * rf); A.w = fmaf(a0, t0.w, A.w * rf);
    A.x = fmaf(a1, t1.x, A.x); A.y = fmaf(a1, t1.y, A.y);
    A.z = fmaf(a1, t1.z, A.z); A.w = fmaf(a1, t1.w, A.w);
    A.x = fmaf(a2, t2.x, A.x); A.y = fmaf(a2, t2.y, A.y);
    A.z = fmaf(a2, t2.z, A.z); A.w = fmaf(a2, t2.w, A.w);
    A.x = fmaf(a3, t3.x, A.x); A.y = fmaf(a3, t3.y, A.y);
    A.z = fmaf(a3, t3.z, A.z); A.w = fmaf(a3, t3.w, A.w);
  }

  // combine the 4 r-subgroups (8 shuffles per node)
  A.x += __shfl_xor(A.x, 16, 64); A.y += __shfl_xor(A.y, 16, 64);
  A.z += __shfl_xor(A.z, 16, 64); A.w += __shfl_xor(A.w, 16, 64);
  A.x += __shfl_xor(A.x, 32, 64); A.y += __shfl_xor(A.y, 32, 64);
  A.z += __shfl_xor(A.z, 32, 64); A.w += __shfl_xor(A.w, 32, 64);

  float inv = 1.f / (d + 1e-16f);
  if (r == 0) {  // 16 lanes, contiguous 256B -> fully coalesced store
    float4 bo4 = *(const float4*)(bo + cb);
    float4 o4;
    o4.x = fmaxf(fmaf(A.x, inv, bo4.x), 0.f);
    o4.y = fmaxf(fmaf(A.y, inv, bo4.y), 0.f);
    o4.z = fmaxf(fmaf(A.z, inv, bo4.z), 0.f);
    o4.w = fmaxf(fmaf(A.w, inv, bo4.w), 0.f);
    *(float4*)(xout + (size_t)n * 64 + cb) = o4;
  }
}

__global__ void k_mean(const float* __restrict__ x, double* __restrict__ meanbuf, int nNodes) {
  __shared__ float sacc[256];
  int lane = threadIdx.x & 63;
  int wv = threadIdx.x >> 6;
  int gw = blockIdx.x * 4 + wv;
  int stride = gridDim.x * 4;
  float acc = 0.f;
  for (int n = gw; n < nNodes; n += stride) acc += x[(size_t)n * 64 + lane];
  sacc[threadIdx.x] = acc;
  __syncthreads();
  if (threadIdx.x < 64) {
    float a = sacc[threadIdx.x] + sacc[threadIdx.x + 64] + sacc[threadIdx.x + 128] + sacc[threadIdx.x + 192];
    atomicAdd(&meanbuf[lane], (double)a);
  }
}

__global__ void k_mlp(const double* __restrict__ meanbuf,
                      const float* __restrict__ Wm1, const float* __restrict__ bm1,
                      const float* __restrict__ Wm2, const float* __restrict__ bm2,
                      const float* __restrict__ Wm3, const float* __restrict__ bm3,
                      float* __restrict__ out, double invN) {
  __shared__ float xm[64];
  __shared__ float h1[32];
  __shared__ float h2[16];
  int t = threadIdx.x;
  xm[t] = (float)(meanbuf[t] * invN);
  __syncthreads();
  if (t < 32) {
    float a = bm1[t];
    for (int c = 0; c < 64; c++) a = fmaf(xm[c], Wm1[c * 32 + t], a);
    h1[t] = fmaxf(a, 0.f);
  }
  __syncthreads();
  if (t < 16) {
    float a = bm2[t];
    for (int c = 0; c < 32; c++) a = fmaf(h1[c], Wm2[c * 16 + t], a);
    h2[t] = fmaxf(a, 0.f);
  }
  __syncthreads();
  if (t == 0) {
    float a = bm3[0];
    for (int c = 0; c < 16; c++) a = fmaf(h2[c], Wm3[c], a);
    out[0] = a;
  }
}

extern "C" void kernel_launch(void* const* d_in, const int* in_sizes, int n_in,
                              void* d_out, int out_size, void* d_ws, size_t ws_size,
                              hipStream_t stream) {
  (void)n_in; (void)out_size; (void)ws_size;
  const int N = in_sizes[0] / 36;   // 50000
  const int E = in_sizes[1];        // 1600000

  const float* feat = (const float*)d_in[0];
  const float* eat  = (const float*)d_in[1];
  const int*   eidx = (const int*)d_in[2];
  const int* src = eidx;
  const int* dst = eidx + E;

  const float* L[4][7];  // Wl, bl, Wr, br, We, att, bo
  for (int l = 0; l < 4; l++)
    for (int j = 0; j < 7; j++) L[l][j] = (const float*)d_in[3 + l * 7 + j];
  const float* Wm1 = (const float*)d_in[31];
  const float* bm1 = (const float*)d_in[32];
  const float* Wm2 = (const float*)d_in[33];
  const float* bm2 = (const float*)d_in[34];
  const float* Wm3 = (const float*)d_in[35];
  const float* bm3 = (const float*)d_in[36];

  const int NBK = (N + 255) >> 8;  // buckets of 256 dst nodes (196)

  // workspace layout (512B aligned)
  char* ws = (char*)d_ws;
  size_t off = 0;
  auto alloc = [&](size_t bytes) {
    off = (off + 511) & ~(size_t)511;
    void* p = ws + off;
    off += bytes;
    return p;
  };
  int*    bkcnt   = (int*)alloc((size_t)NBK * 16 * 4);  // 1 counter per 64B line
  int*    bcur    = (int*)alloc((size_t)NBK * 16 * 4);  // 1 counter per 64B line
  double* meanbuf = (double*)alloc(64 * 8);
  size_t zero_bytes = off;  // bkcnt + bcur + meanbuf
  int*    boffs   = (int*)alloc((size_t)(NBK + 1) * 4);
  int*    rowptr  = (int*)alloc((size_t)(N + 1) * 4);
  int2*   pairs   = (int2*)alloc((size_t)E * 8);
  float*  xA      = (float*)alloc((size_t)N * 64 * 4);  // xl
  float*  xB      = (float*)alloc((size_t)N * 64 * 4);  // xr
  float*  xC      = (float*)alloc((size_t)N * 64 * 4);  // layer out / next in
  uint2*  tmp     = (uint2*)xC;  // aliases xC: dead until k_edge layer 1 writes it

  hipMemsetAsync(d_ws, 0, zero_bytes, stream);

  const int TILES = 4;           // 64 nodes per transform block
  int sgrid = (E + 4095) / 4096; // 4096 edges per 256-thr block
  int tgrid = (N + 16 * TILES - 1) / (16 * TILES);
  int ngrid = (N + 3) / 4;       // k_edge: 4 nodes (waves) per 256-thr block

  k_bcount<<<sgrid, 256, 0, stream>>>(dst, bkcnt, E, NBK);
  k_bscan<<<1, 256, 0, stream>>>(bkcnt, boffs, NBK, E);
  k_scatter<<<sgrid, 256, 0, stream>>>(src, dst, eat, boffs, bcur, tmp, E, NBK);
  k_csr<<<NBK, 256, 0, stream>>>(boffs, tmp, pairs, rowptr, N);

  for (int l = 0; l < 4; l++) {
    if (l == 0)
      k_transform<36, TILES><<<tgrid, 256, 0, stream>>>(feat, L[0][0], L[0][1], L[0][2], L[0][3], xA, xB, N);
    else
      k_transform<64, TILES><<<tgrid, 256, 0, stream>>>(xC, L[l][0], L[l][1], L[l][2], L[l][3], xA, xB, N);
    k_edge<<<ngrid, 256, 0, stream>>>(xA, xB, rowptr, pairs,
                                      L[l][4], L[l][5], L[l][6], xC, N);
  }

  k_mean<<<256, 256, 0, stream>>>(xC, meanbuf, N);
  k_mlp<<<1, 64, 0, stream>>>(meanbuf, Wm1, bm1, Wm2, bm2, Wm3, bm3, (float*)d_out, 1.0 / (double)N);
}

// Round 13
// 497.613 us; speedup vs baseline: 1.5123x; 1.0440x over previous
//
#include <hip/hip_runtime.h>

// ---------------------------------------------------------------------------
// GATv2 x4 + MLP readout.  R13 = R12 with build shortened + reg-tiled xform.
//   CSR build (2 passes over edges total):
//     k_scatter: LDS-binned scatter into FIXED-CAPACITY bucket regions
//       (CAP=10240 >> mean 8163, >20 sigma; no pre-count pass needed).
//       ~77k spread global atomics (R5 lesson: per-edge atomics on few
//       lines serialize ~11ns/op; block-aggregated padded counters free).
//     k_bscan: 1 block scans 196 bucket counts (from bcur) -> boffs.
//     k_csr: per bucket: LDS per-node histogram + scan -> rowptr direct;
//       then scatters records to final CSR positions (records L2-hot).
//   k_transform: 64 nodes/block, thread = 4 nodes x 4 cols: 2 ds_read_b128
//     weight reads feed 32 fma (R12 version fed 8 -> DS-pipe-bound ~21us).
//   k_edge (FROZEN, R11/R12-proven 56.5us: FETCH 159MB WRITE 12.5MB
//     VALU 77%): zero LDS, lane=(c4,r), per-lane edge records, coalesced
//     quarter-wave row gathers, register aggregate, zero alpha shuffles,
//     launch_bounds(256,5) (R9 lesson: 64-VGPR cap -> scratch spills).
// Readout: f64-atomic mean + 1-block MLP.   N <= 65536 packing assumption.
// R7 lesson: per-lane-gather lds-DMA explodes HBM traffic; keep VMEM
//   gathers with full-row lane coverage.
// ---------------------------------------------------------------------------

__device__ __forceinline__ int rfl(int v) { return __builtin_amdgcn_readfirstlane(v); }

#define NBK_MAX 256
#define BCAP 10240

// ---- pass 1: block-binned scatter into fixed-capacity bucket regions
__global__ void __launch_bounds__(256) k_scatter(
    const int* __restrict__ src, const int* __restrict__ dst,
    const float* __restrict__ ea_in,
    int* __restrict__ bcur, uint2* __restrict__ tmp, int E, int nbk) {
  __shared__ int cnt[NBK_MAX];
  __shared__ int cur[NBK_MAX];
  __shared__ int gbase[NBK_MAX];
  int tid = threadIdx.x;
  if (tid < nbk) { cnt[tid] = 0; cur[tid] = 0; }
  __syncthreads();
  int base = blockIdx.x * 4096 + tid;
  uint2 rec[16];
  #pragma unroll
  for (int k = 0; k < 16; k++) {
    int e = base + k * 256;
    if (e < E) {
      unsigned d = (unsigned)dst[e];
      rec[k] = make_uint2((d << 16) | (unsigned)src[e],
                          (unsigned)__float_as_int(ea_in[e]));
      atomicAdd(&cnt[d >> 8], 1);
    } else {
      rec[k] = make_uint2(0u, 0u);
    }
  }
  __syncthreads();
  if (tid < nbk) {
    int c = cnt[tid];
    gbase[tid] = (c > 0) ? atomicAdd(&bcur[tid * 16], c) : 0;  // padded ctr
  }
  __syncthreads();
  #pragma unroll
  for (int k = 0; k < 16; k++) {
    int e = base + k * 256;
    if (e < E) {
      int b = (int)(rec[k].x >> 24);
      int slot = atomicAdd(&cur[b], 1);
      tmp[(size_t)b * BCAP + gbase[b] + slot] = rec[k];
    }
  }
}

// ---- scan 196 bucket counts -> boffs[0..nbk]
__global__ void k_bscan(const int* __restrict__ bcur, int* __restrict__ boffs,
                        int nbk, int E) {
  __shared__ int wsum[4];
  int tid = threadIdx.x, lane = tid & 63, wv = tid >> 6;
  int v = (tid < nbk) ? bcur[tid * 16] : 0;
  int x = v;
  #pragma unroll
  for (int o = 1; o < 64; o <<= 1) {
    int t = __shfl_up(x, o, 64);
    if (lane >= o) x += t;
  }
  if (lane == 63) wsum[wv] = x;
  __syncthreads();
  int wo = 0;
  for (int k = 0; k < 4; k++) if (k < wv) wo += wsum[k];
  if (tid < nbk) boffs[tid] = wo + (x - v);
  if (tid == 0) boffs[nbk] = E;
}

// ---- pass 2: per bucket: LDS node-histogram + scan -> rowptr; then scatter
__global__ void __launch_bounds__(256) k_csr(const int* __restrict__ bcur,
                                             const int* __restrict__ boffs,
                                             const uint2* __restrict__ tmp,
                                             int2* __restrict__ pairs,
                                             int* __restrict__ rowptr, int N) {
  __shared__ int cnt[256];
  __shared__ int pref[256];
  __shared__ int cur[256];
  __shared__ int wsum[4];
  int b = blockIdx.x;
  int n0 = b << 8;
  int tid = threadIdx.x, lane = tid & 63, wv = tid >> 6;
  cnt[tid] = 0;
  cur[tid] = 0;
  __syncthreads();
  int cb = bcur[b * 16];
  const uint2* tb = tmp + (size_t)b * BCAP;
  int lo = boffs[b];
  for (int k = tid; k < cb; k += 256)
    atomicAdd(&cnt[(int)(tb[k].x >> 16) - n0], 1);
  __syncthreads();
  int v = cnt[tid];
  int x = v;
  #pragma unroll
  for (int o = 1; o < 64; o <<= 1) {
    int t = __shfl_up(x, o, 64);
    if (lane >= o) x += t;
  }
  if (lane == 63) wsum[wv] = x;
  __syncthreads();
  int wo = 0;
  for (int k = 0; k < 4; k++) if (k < wv) wo += wsum[k];
  int start = lo + wo + (x - v);   // exclusive prefix -> global CSR start
  pref[tid] = start;
  int nn = n0 + tid;
  if (nn <= N) rowptr[nn] = start; // boundary lane writes rowptr[N] = E
  __syncthreads();
  for (int k = tid; k < cb; k += 256) {
    uint2 rec = tb[k];
    int local = (int)(rec.x >> 16) - n0;
    int pos = pref[local] + atomicAdd(&cur[local], 1);
    pairs[pos] = make_int2((int)(rec.x & 0xffffu), (int)rec.y);
  }
}

// xl = x @ Wl + bl ; xr = x @ Wr + br.  64 nodes/block; thread = 4n x 4c.
// 2 ds_read_b128 weight reads amortized over 32 fma; x read via broadcast.
template <int DIN>
__global__ void __launch_bounds__(256) k_transform(
    const float* __restrict__ x, const float* __restrict__ Wl, const float* __restrict__ bl,
    const float* __restrict__ Wr, const float* __restrict__ br,
    float* __restrict__ xl, float* __restrict__ xr, int nNodes) {
  __shared__ __align__(16) float sWl[DIN * 64];
  __shared__ __align__(16) float sWr[DIN * 64];
  __shared__ float sx[64][DIN + 1];
  int tid = threadIdx.x;
  for (int i = tid; i < DIN * 64; i += 256) { sWl[i] = Wl[i]; sWr[i] = Wr[i]; }
  int nb = blockIdx.x * 64;
  for (int i = tid; i < 64 * DIN; i += 256) {
    int ln = i / DIN, c = i % DIN;   // coalesced global read
    int g = nb + ln;
    sx[ln][c] = (g < nNodes) ? x[(size_t)g * DIN + c] : 0.f;
  }
  __syncthreads();
  int c4 = (tid & 15) * 4;     // col group
  int ns = (tid >> 4) * 4;     // first of 4 nodes
  float4 bl4 = *(const float4*)(bl + c4);
  float4 br4 = *(const float4*)(br + c4);
  float4 L0 = bl4, L1 = bl4, L2 = bl4, L3 = bl4;
  float4 R0 = br4, R1 = br4, R2 = br4, R3 = br4;
  const float* x0 = sx[ns + 0];
  const float* x1 = sx[ns + 1];
  const float* x2 = sx[ns + 2];
  const float* x3 = sx[ns + 3];
  #pragma unroll 4
  for (int k = 0; k < DIN; k++) {
    float4 wl = *(const float4*)(sWl + k * 64 + c4);
    float4 wr = *(const float4*)(sWr + k * 64 + c4);
    float a = x0[k], bb = x1[k], c = x2[k], dd = x3[k];
    L0.x = fmaf(a, wl.x, L0.x);  L0.y = fmaf(a, wl.y, L0.y);
    L0.z = fmaf(a, wl.z, L0.z);  L0.w = fmaf(a, wl.w, L0.w);
    R0.x = fmaf(a, wr.x, R0.x);  R0.y = fmaf(a, wr.y, R0.y);
    R0.z = fmaf(a, wr.z, R0.z);  R0.w = fmaf(a, wr.w, R0.w);
    L1.x = fmaf(bb, wl.x, L1.x); L1.y = fmaf(bb, wl.y, L1.y);
    L1.z = fmaf(bb, wl.z, L1.z); L1.w = fmaf(bb, wl.w, L1.w);
    R1.x = fmaf(bb, wr.x, R1.x); R1.y = fmaf(bb, wr.y, R1.y);
    R1.z = fmaf(bb, wr.z, R1.z); R1.w = fmaf(bb, wr.w, R1.w);
    L2.x = fmaf(c, wl.x, L2.x);  L2.y = fmaf(c, wl.y, L2.y);
    L2.z = fmaf(c, wl.z, L2.z);  L2.w = fmaf(c, wl.w, L2.w);
    R2.x = fmaf(c, wr.x, R2.x);  R2.y = fmaf(c, wr.y, R2.y);
    R2.z = fmaf(c, wr.z, R2.z);  R2.w = fmaf(c, wr.w, R2.w);
    L3.x = fmaf(dd, wl.x, L3.x); L3.y = fmaf(dd, wl.y, L3.y);
    L3.z = fmaf(dd, wl.z, L3.z); L3.w = fmaf(dd, wl.w, L3.w);
    R3.x = fmaf(dd, wr.x, R3.x); R3.y = fmaf(dd, wr.y, R3.y);
    R3.z = fmaf(dd, wr.z, R3.z); R3.w = fmaf(dd, wr.w, R3.w);
  }
  int g = nb + ns;
  if (g + 0 < nNodes) { *(float4*)(xl + (size_t)(g+0)*64 + c4) = L0; *(float4*)(xr + (size_t)(g+0)*64 + c4) = R0; }
  if (g + 1 < nNodes) { *(float4*)(xl + (size_t)(g+1)*64 + c4) = L1; *(float4*)(xr + (size_t)(g+1)*64 + c4) = R1; }
  if (g + 2 < nNodes) { *(float4*)(xl + (size_t)(g+2)*64 + c4) = L2; *(float4*)(xr + (size_t)(g+2)*64 + c4) = R2; }
  if (g + 3 < nNodes) { *(float4*)(xl + (size_t)(g+3)*64 + c4) = L3; *(float4*)(xr + (size_t)(g+3)*64 + c4) = R3; }
}

// Fused score + online softmax + aggregate.  One wave per node, chunk = 16,
// zero LDS, register aggregate with zero alpha shuffles.  (FROZEN.)
#define SC1(T, EA, OUT) { float u, acc; \
  u = T.x + fmaf(EA, We4.x, xr4.x); u = fmaxf(u, 0.2f * u); acc = at4.x * u; \
  u = T.y + fmaf(EA, We4.y, xr4.y); u = fmaxf(u, 0.2f * u); acc = fmaf(at4.y, u, acc); \
  u = T.z + fmaf(EA, We4.z, xr4.z); u = fmaxf(u, 0.2f * u); acc = fmaf(at4.z, u, acc); \
  u = T.w + fmaf(EA, We4.w, xr4.w); u = fmaxf(u, 0.2f * u); acc = fmaf(at4.w, u, acc); \
  OUT = acc; }

__global__ void __launch_bounds__(256, 5) k_edge(
    const float* __restrict__ xl, const float* __restrict__ xr,
    const int* __restrict__ rowptr, const int2* __restrict__ pairs,
    const float* __restrict__ We, const float* __restrict__ att,
    const float* __restrict__ bo, float* __restrict__ xout, int nNodes) {
  int lane = threadIdx.x & 63;
  int wv = rfl((int)(threadIdx.x >> 6));
  int n = rfl(blockIdx.x * 4 + wv);
  if (n >= nNodes) return;
  int c4 = lane & 15;   // channel group
  int r  = lane >> 4;   // edge subgroup (0..3); lane owns edges {4i+r}
  int cb = c4 * 4;      // first channel

  float4 We4 = *(const float4*)(We + cb);
  float4 at4 = *(const float4*)(att + cb);
  float4 xr4 = *(const float4*)(xr + (size_t)n * 64 + cb);
  int s0 = rfl(rowptr[n]);
  int s1 = rfl(rowptr[n + 1]);
  int last = s1 - 1;

  float m = -3.0e38f, d = 0.f;
  float4 A = {0.f, 0.f, 0.f, 0.f};

  for (int kb = s0; kb < s1; kb += 16) {
    int cnt = rfl(min(16, s1 - kb));
    // each lane loads its own 4 edge records (same-r lanes broadcast)
    int2 p0 = pairs[min(kb + r,      last)];
    int2 p1 = pairs[min(kb + 4 + r,  last)];
    int2 p2 = pairs[min(kb + 8 + r,  last)];
    int2 p3 = pairs[min(kb + 12 + r, last)];
    float ea0 = __int_as_float(p0.y);
    float ea1 = __int_as_float(p1.y);
    float ea2 = __int_as_float(p2.y);
    float ea3 = __int_as_float(p3.y);

    // coalesced row gathers: 16 same-r lanes cover the full 256B row
    float4 t0 = *(const float4*)(xl + (size_t)(unsigned)p0.x * 64 + cb);
    float4 t1 = *(const float4*)(xl + (size_t)(unsigned)p1.x * 64 + cb);
    float4 t2 = *(const float4*)(xl + (size_t)(unsigned)p2.x * 64 + cb);
    float4 t3 = *(const float4*)(xl + (size_t)(unsigned)p3.x * 64 + cb);

    // per-lane 4-channel partial dots
    float sc0, sc1, sc2, sc3;
    SC1(t0, ea0, sc0)
    SC1(t1, ea1, sc1)
    SC1(t2, ea2, sc2)
    SC1(t3, ea3, sc3)

    // complete the dots: butterfly over the 16 c4-lanes
    #pragma unroll
    for (int o = 1; o <= 8; o <<= 1) {
      sc0 += __shfl_xor(sc0, o, 64);
      sc1 += __shfl_xor(sc1, o, 64);
      sc2 += __shfl_xor(sc2, o, 64);
      sc3 += __shfl_xor(sc3, o, 64);
    }
    // mask padded edges (4i + r >= cnt) -> alpha = 0
    sc0 = (r < cnt)      ? sc0 : -3.0e38f;
    sc1 = (4 + r < cnt)  ? sc1 : -3.0e38f;
    sc2 = (8 + r < cnt)  ? sc2 : -3.0e38f;
    sc3 = (12 + r < cnt) ? sc3 : -3.0e38f;

    // online softmax (cross-lane only over r: offsets 16, 32)
    float mc = fmaxf(fmaxf(sc0, sc1), fmaxf(sc2, sc3));
    mc = fmaxf(mc, __shfl_xor(mc, 16, 64));
    mc = fmaxf(mc, __shfl_xor(mc, 32, 64));
    float newm = fmaxf(m, mc);
    float rf = __expf(m - newm);     // 0 on first chunk, 1 if max unchanged
    float a0 = __expf(sc0 - newm);
    float a1 = __expf(sc1 - newm);
    float a2 = __expf(sc2 - newm);
    float a3 = __expf(sc3 - newm);
    float ds = (a0 + a1) + (a2 + a3);
    ds += __shfl_xor(ds, 16, 64);
    ds += __shfl_xor(ds, 32, 64);
    d = d * rf + ds;
    m = newm;

    // aggregate in registers: this lane computed its own alphas
    A.x = fmaf(a0, t0.x, A.x * rf); A.y = fmaf(a0, t0.y, A.y * rf);
    A.z = fmaf(a0, t0.z, A.z * rf); A.w = fmaf(a0, t0.w, A.w * rf);
    A.x = fmaf(a1, t1.x, A.x); A.y = fmaf(a1, t1.y, A.y);
    A.z = fmaf(a1, t1.z, A.z); A.w = fmaf(a1, t1.w, A.w);
    A.x = fmaf(a2, t2.x, A.x); A.y = fmaf(a2, t2.y, A.y);
    A.z = fmaf(a2, t2.z, A.z); A.w = fmaf(a2, t2.w, A.w);
    A.x = fmaf(a3, t3.x, A.x); A.y = fmaf(a3, t3.y, A.y);
    A.z = fmaf(a3, t3.z, A.z); A.w = fmaf(a3, t3.w, A.w);
  }

  // combine the 4 r-subgroups (8 shuffles per node)
  A.x += __shfl_xor(A.x, 16, 64); A.y += __shfl_xor(A.y, 16, 64);
  A.z += __shfl_xor(A.z, 16, 64); A.w += __shfl_xor(A.w, 16, 64);
  A.x += __shfl_xor(A.x, 32, 64); A.y += __shfl_xor(A.y, 32, 64);
  A.z += __shfl_xor(A.z, 32, 64); A.w += __shfl_xor(A.w, 32, 64);

  float inv = 1.f / (d + 1e-16f);
  if (r == 0) {  // 16 lanes, contiguous 256B -> fully coalesced store
    float4 bo4 = *(const float4*)(bo + cb);
    float4 o4;
    o4.x = fmaxf(fmaf(A.x, inv, bo4.x), 0.f);
    o4.y = fmaxf(fmaf(A.y, inv, bo4.y), 0.f);
    o4.z = fmaxf(fmaf(A.z, inv, bo4.z), 0.f);
    o4.w = fmaxf(fmaf(A.w, inv, bo4.w), 0.f);
    *(float4*)(xout + (size_t)n * 64 + cb) = o4;
  }
}

__global__ void k_mean(const float* __restrict__ x, double* __restrict__ meanbuf, int nNodes) {
  __shared__ float sacc[256];
  int lane = threadIdx.x & 63;
  int wv = threadIdx.x >> 6;
  int gw = blockIdx.x * 4 + wv;
  int stride = gridDim.x * 4;
  float acc = 0.f;
  for (int n = gw; n < nNodes; n += stride) acc += x[(size_t)n * 64 + lane];
  sacc[threadIdx.x] = acc;
  __syncthreads();
  if (threadIdx.x < 64) {
    float a = sacc[threadIdx.x] + sacc[threadIdx.x + 64] + sacc[threadIdx.x + 128] + sacc[threadIdx.x + 192];
    atomicAdd(&meanbuf[lane], (double)a);
  }
}

__global__ void k_mlp(const double* __restrict__ meanbuf,
                      const float* __restrict__ Wm1, const float* __restrict__ bm1,
                      const float* __restrict__ Wm2, const float* __restrict__ bm2,
                      const float* __restrict__ Wm3, const float* __restrict__ bm3,
                      float* __restrict__ out, double invN) {
  __shared__ float xm[64];
  __shared__ float h1[32];
  __shared__ float h2[16];
  int t = threadIdx.x;
  xm[t] = (float)(meanbuf[t] * invN);
  __syncthreads();
  if (t < 32) {
    float a = bm1[t];
    for (int c = 0; c < 64; c++) a = fmaf(xm[c], Wm1[c * 32 + t], a);
    h1[t] = fmaxf(a, 0.f);
  }
  __syncthreads();
  if (t < 16) {
    float a = bm2[t];
    for (int c = 0; c < 32; c++) a = fmaf(h1[c], Wm2[c * 16 + t], a);
    h2[t] = fmaxf(a, 0.f);
  }
  __syncthreads();
  if (t == 0) {
    float a = bm3[0];
    for (int c = 0; c < 16; c++) a = fmaf(h2[c], Wm3[c], a);
    out[0] = a;
  }
}

extern "C" void kernel_launch(void* const* d_in, const int* in_sizes, int n_in,
                              void* d_out, int out_size, void* d_ws, size_t ws_size,
                              hipStream_t stream) {
  (void)n_in; (void)out_size; (void)ws_size;
  const int N = in_sizes[0] / 36;   // 50000
  const int E = in_sizes[1];        // 1600000

  const float* feat = (const float*)d_in[0];
  const float* eat  = (const float*)d_in[1];
  const int*   eidx = (const int*)d_in[2];
  const int* src = eidx;
  const int* dst = eidx + E;

  const float* L[4][7];  // Wl, bl, Wr, br, We, att, bo
  for (int l = 0; l < 4; l++)
    for (int j = 0; j < 7; j++) L[l][j] = (const float*)d_in[3 + l * 7 + j];
  const float* Wm1 = (const float*)d_in[31];
  const float* bm1 = (const float*)d_in[32];
  const float* Wm2 = (const float*)d_in[33];
  const float* bm2 = (const float*)d_in[34];
  const float* Wm3 = (const float*)d_in[35];
  const float* bm3 = (const float*)d_in[36];

  const int NBK = (N + 255) >> 8;  // buckets of 256 dst nodes (196)

  // workspace layout (512B aligned)
  char* ws = (char*)d_ws;
  size_t off = 0;
  auto alloc = [&](size_t bytes) {
    off = (off + 511) & ~(size_t)511;
    void* p = ws + off;
    off += bytes;
    return p;
  };
  int*    bcur    = (int*)alloc((size_t)NBK * 16 * 4);  // 1 counter per 64B line
  double* meanbuf = (double*)alloc(64 * 8);
  size_t zero_bytes = off;  // bcur + meanbuf
  int*    boffs   = (int*)alloc((size_t)(NBK + 1) * 4);
  int*    rowptr  = (int*)alloc((size_t)(N + 1) * 4);
  int2*   pairs   = (int2*)alloc((size_t)E * 8);
  float*  xA      = (float*)alloc((size_t)N * 64 * 4);  // xl
  float*  xB      = (float*)alloc((size_t)N * 64 * 4);  // xr
  float*  xC      = (float*)alloc((size_t)N * 64 * 4);  // layer out / next in
  // tmp (16.06 MB, NBK*BCAP records) aliases xB..xC: both dead until the
  // first k_transform (xB) / first k_edge (xC), which run after k_csr.
  uint2*  tmp     = (uint2*)xB;

  hipMemsetAsync(d_ws, 0, zero_bytes, stream);

  int sgrid = (E + 4095) / 4096; // 4096 edges per 256-thr block
  int tgrid = (N + 63) / 64;     // k_transform: 64 nodes per 256-thr block
  int ngrid = (N + 3) / 4;       // k_edge: 4 nodes (waves) per 256-thr block

  k_scatter<<<sgrid, 256, 0, stream>>>(src, dst, eat, bcur, tmp, E, NBK);
  k_bscan<<<1, 256, 0, stream>>>(bcur, boffs, NBK, E);
  k_csr<<<NBK, 256, 0, stream>>>(bcur, boffs, tmp, pairs, rowptr, N);

  for (int l = 0; l < 4; l++) {
    if (l == 0)
      k_transform<36><<<tgrid, 256, 0, stream>>>(feat, L[0][0], L[0][1], L[0][2], L[0][3], xA, xB, N);
    else
      k_transform<64><<<tgrid, 256, 0, stream>>>(xC, L[l][0], L[l][1], L[l][2], L[l][3], xA, xB, N);
    k_edge<<<ngrid, 256, 0, stream>>>(xA, xB, rowptr, pairs,
                                      L[l][4], L[l][5], L[l][6], xC, N);
  }

  k_mean<<<256, 256, 0, stream>>>(xC, meanbuf, N);
  k_mlp<<<1, 64, 0, stream>>>(meanbuf, Wm1, bm1, Wm2, bm2, Wm3, bm3, (float*)d_out, 1.0 / (double)N);
}

// Round 14
// 490.799 us; speedup vs baseline: 1.5333x; 1.0139x over previous
//
#include <hip/hip_runtime.h>

// ---------------------------------------------------------------------------
// GATv2 x4 + MLP readout.  R14 = R13 with the build chain overlapped.
//   k_build1 (fused, heterogeneous): blocks [0,SG) scatter 2048 edges each
//     into fixed-capacity bucket regions (LDS-binned, ~154k spread global
//     atomics on padded lines); blocks [SG,SG+TG) run transform layer 1
//     (independent work -> hides ~15us under the scatter's shadow).
//   k_csr (1024 thr, scan folded in): per bucket: lo = masked block-reduce
//     of bucket counts; LDS per-node histogram + scan -> rowptr direct;
//     scatter records to final CSR positions (records L2-hot).  8 serial
//     iters/pass instead of 32 (R13), 16 waves hide load->atomic chains.
//   k_edge (FROZEN, 55us: FETCH 159MB WRITE 12.5MB VALU ~75%): zero LDS,
//     lane=(c4,r), per-lane edge records, coalesced quarter-wave row
//     gathers, register aggregate, zero alpha shuffles, bounds(256,5)
//     (R9 lesson: 64-VGPR cap -> scratch spills, +170MB HBM traffic).
//   k_transform (layers 2-4): 64 nodes/block, thread = 4n x 4c (R13).
// Readout: f64-atomic mean + 1-block MLP.   N <= 65536 packing assumption.
// R5 lesson: per-edge atomics on few lines serialize ~11ns/op.
// R7 lesson: per-lane-gather lds-DMA explodes HBM; keep VMEM gathers with
//   full-row lane coverage.
// ---------------------------------------------------------------------------

__device__ __forceinline__ int rfl(int v) { return __builtin_amdgcn_readfirstlane(v); }

#define NBK_MAX 256
#define BCAP 9216   // mean bucket fill 8163, margin ~11.7 sigma

// ---- fused: scatter (blocks < SG) + transform layer 1 (blocks >= SG)
__global__ void __launch_bounds__(256) k_build1(
    const int* __restrict__ src, const int* __restrict__ dst,
    const float* __restrict__ ea_in, int* __restrict__ bcur,
    uint2* __restrict__ tmp, int E, int nbk, int SG,
    const float* __restrict__ x, const float* __restrict__ Wl,
    const float* __restrict__ bl, const float* __restrict__ Wr,
    const float* __restrict__ br, float* __restrict__ xl,
    float* __restrict__ xr, int nNodes) {
  __shared__ __align__(16) float smem[6976];  // 27.9 KB union
  int tid = threadIdx.x;
  if ((int)blockIdx.x < SG) {
    // ---------------- scatter role: 2048 edges per block ----------------
    int* cnt = (int*)smem;
    int* cur = cnt + 256;
    int* gb  = cur + 256;
    if (tid < nbk) { cnt[tid] = 0; cur[tid] = 0; }
    __syncthreads();
    int base = blockIdx.x * 2048 + tid;
    uint2 rec[8];
    #pragma unroll
    for (int k = 0; k < 8; k++) {
      int e = base + k * 256;
      if (e < E) {
        unsigned d = (unsigned)dst[e];
        rec[k] = make_uint2((d << 16) | (unsigned)src[e],
                            (unsigned)__float_as_int(ea_in[e]));
        atomicAdd(&cnt[d >> 8], 1);
      } else {
        rec[k] = make_uint2(0u, 0u);
      }
    }
    __syncthreads();
    if (tid < nbk) {
      int c = cnt[tid];
      gb[tid] = (c > 0) ? atomicAdd(&bcur[tid * 16], c) : 0;  // padded ctr
    }
    __syncthreads();
    #pragma unroll
    for (int k = 0; k < 8; k++) {
      int e = base + k * 256;
      if (e < E) {
        int b = (int)(rec[k].x >> 24);  // == dst >> 8
        int slot = atomicAdd(&cur[b], 1);
        tmp[(size_t)b * BCAP + gb[b] + slot] = rec[k];
      }
    }
  } else {
    // ---------------- transform layer-1 role (DIN = 36) ----------------
    const int DIN = 36;
    float* sWl = smem;                                   // 2304 floats
    float* sWr = smem + 2304;                            // 2304 floats
    float (*sx)[DIN + 1] = (float(*)[DIN + 1])(smem + 4608);  // 64 x 37
    for (int i = tid; i < DIN * 64; i += 256) { sWl[i] = Wl[i]; sWr[i] = Wr[i]; }
    int nb = ((int)blockIdx.x - SG) * 64;
    for (int i = tid; i < 64 * DIN; i += 256) {
      int ln = i / DIN, c = i % DIN;
      int g = nb + ln;
      sx[ln][c] = (g < nNodes) ? x[(size_t)g * DIN + c] : 0.f;
    }
    __syncthreads();
    int c4 = (tid & 15) * 4;
    int ns = (tid >> 4) * 4;
    float4 bl4 = *(const float4*)(bl + c4);
    float4 br4 = *(const float4*)(br + c4);
    float4 L0 = bl4, L1 = bl4, L2 = bl4, L3 = bl4;
    float4 R0 = br4, R1 = br4, R2 = br4, R3 = br4;
    const float* x0 = sx[ns + 0];
    const float* x1 = sx[ns + 1];
    const float* x2 = sx[ns + 2];
    const float* x3 = sx[ns + 3];
    #pragma unroll 4
    for (int k = 0; k < DIN; k++) {
      float4 wl = *(const float4*)(sWl + k * 64 + c4);
      float4 wr = *(const float4*)(sWr + k * 64 + c4);
      float a = x0[k], bb = x1[k], c = x2[k], dd = x3[k];
      L0.x = fmaf(a, wl.x, L0.x);  L0.y = fmaf(a, wl.y, L0.y);
      L0.z = fmaf(a, wl.z, L0.z);  L0.w = fmaf(a, wl.w, L0.w);
      R0.x = fmaf(a, wr.x, R0.x);  R0.y = fmaf(a, wr.y, R0.y);
      R0.z = fmaf(a, wr.z, R0.z);  R0.w = fmaf(a, wr.w, R0.w);
      L1.x = fmaf(bb, wl.x, L1.x); L1.y = fmaf(bb, wl.y, L1.y);
      L1.z = fmaf(bb, wl.z, L1.z); L1.w = fmaf(bb, wl.w, L1.w);
      R1.x = fmaf(bb, wr.x, R1.x); R1.y = fmaf(bb, wr.y, R1.y);
      R1.z = fmaf(bb, wr.z, R1.z); R1.w = fmaf(bb, wr.w, R1.w);
      L2.x = fmaf(c, wl.x, L2.x);  L2.y = fmaf(c, wl.y, L2.y);
      L2.z = fmaf(c, wl.z, L2.z);  L2.w = fmaf(c, wl.w, L2.w);
      R2.x = fmaf(c, wr.x, R2.x);  R2.y = fmaf(c, wr.y, R2.y);
      R2.z = fmaf(c, wr.z, R2.z);  R2.w = fmaf(c, wr.w, R2.w);
      L3.x = fmaf(dd, wl.x, L3.x); L3.y = fmaf(dd, wl.y, L3.y);
      L3.z = fmaf(dd, wl.z, L3.z); L3.w = fmaf(dd, wl.w, L3.w);
      R3.x = fmaf(dd, wr.x, R3.x); R3.y = fmaf(dd, wr.y, R3.y);
      R3.z = fmaf(dd, wr.z, R3.z); R3.w = fmaf(dd, wr.w, R3.w);
    }
    int g = nb + ns;
    if (g + 0 < nNodes) { *(float4*)(xl + (size_t)(g+0)*64 + c4) = L0; *(float4*)(xr + (size_t)(g+0)*64 + c4) = R0; }
    if (g + 1 < nNodes) { *(float4*)(xl + (size_t)(g+1)*64 + c4) = L1; *(float4*)(xr + (size_t)(g+1)*64 + c4) = R1; }
    if (g + 2 < nNodes) { *(float4*)(xl + (size_t)(g+2)*64 + c4) = L2; *(float4*)(xr + (size_t)(g+2)*64 + c4) = R2; }
    if (g + 3 < nNodes) { *(float4*)(xl + (size_t)(g+3)*64 + c4) = L3; *(float4*)(xr + (size_t)(g+3)*64 + c4) = R3; }
  }
}

// ---- per bucket (1024 thr): offset reduce + node histogram/scan -> rowptr,
//      then scatter to final CSR positions.
__global__ void __launch_bounds__(1024) k_csr(const int* __restrict__ bcur,
                                              const uint2* __restrict__ tmp,
                                              int2* __restrict__ pairs,
                                              int* __restrict__ rowptr,
                                              int N, int nbk) {
  __shared__ int cnt[256];
  __shared__ int pref[256];
  __shared__ int cur[256];
  __shared__ int wsum[16];
  __shared__ int lo_s;
  int b = blockIdx.x;
  int n0 = b << 8;
  int tid = threadIdx.x, lane = tid & 63, wv = tid >> 6;
  if (tid < 256) { cnt[tid] = 0; cur[tid] = 0; }
  // lo = sum of counts of buckets before b (masked block reduce)
  int contrib = (tid < nbk && tid < b) ? bcur[tid * 16] : 0;
  #pragma unroll
  for (int o = 32; o > 0; o >>= 1) contrib += __shfl_xor(contrib, o, 64);
  if (lane == 0) wsum[wv] = contrib;
  __syncthreads();
  if (tid == 0) {
    int s = 0;
    for (int i = 0; i < 16; i++) s += wsum[i];
    lo_s = s;
  }
  __syncthreads();
  int lo = lo_s;
  int cb = bcur[b * 16];
  const uint2* tb = tmp + (size_t)b * BCAP;
  for (int k = tid; k < cb; k += 1024)
    atomicAdd(&cnt[(int)(tb[k].x >> 16) - n0], 1);
  __syncthreads();
  int v = 0, x = 0;
  if (tid < 256) {             // waves 0..3: scan the 256 node counts
    v = cnt[tid];
    x = v;
    #pragma unroll
    for (int o = 1; o < 64; o <<= 1) {
      int t = __shfl_up(x, o, 64);
      if (lane >= o) x += t;
    }
    if (lane == 63) wsum[wv] = x;
  }
  __syncthreads();
  if (tid < 256) {
    int wo = 0;
    for (int k = 0; k < 4; k++) if (k < wv) wo += wsum[k];
    int start = lo + wo + (x - v);
    pref[tid] = start;
    int nn = n0 + tid;
    if (nn <= N) rowptr[nn] = start;  // boundary lane writes rowptr[N] = E
  }
  __syncthreads();
  for (int k = tid; k < cb; k += 1024) {
    uint2 rec = tb[k];
    int local = (int)(rec.x >> 16) - n0;
    int pos = pref[local] + atomicAdd(&cur[local], 1);
    pairs[pos] = make_int2((int)(rec.x & 0xffffu), (int)rec.y);
  }
}

// xl = x @ Wl + bl ; xr = x @ Wr + br.  64 nodes/block; thread = 4n x 4c.
// (R13-proven; used for layers 2-4, DIN = 64.)
template <int DIN>
__global__ void __launch_bounds__(256) k_transform(
    const float* __restrict__ x, const float* __restrict__ Wl, const float* __restrict__ bl,
    const float* __restrict__ Wr, const float* __restrict__ br,
    float* __restrict__ xl, float* __restrict__ xr, int nNodes) {
  __shared__ __align__(16) float sWl[DIN * 64];
  __shared__ __align__(16) float sWr[DIN * 64];
  __shared__ float sx[64][DIN + 1];
  int tid = threadIdx.x;
  for (int i = tid; i < DIN * 64; i += 256) { sWl[i] = Wl[i]; sWr[i] = Wr[i]; }
  int nb = blockIdx.x * 64;
  for (int i = tid; i < 64 * DIN; i += 256) {
    int ln = i / DIN, c = i % DIN;
    int g = nb + ln;
    sx[ln][c] = (g < nNodes) ? x[(size_t)g * DIN + c] : 0.f;
  }
  __syncthreads();
  int c4 = (tid & 15) * 4;
  int ns = (tid >> 4) * 4;
  float4 bl4 = *(const float4*)(bl + c4);
  float4 br4 = *(const float4*)(br + c4);
  float4 L0 = bl4, L1 = bl4, L2 = bl4, L3 = bl4;
  float4 R0 = br4, R1 = br4, R2 = br4, R3 = br4;
  const float* x0 = sx[ns + 0];
  const float* x1 = sx[ns + 1];
  const float* x2 = sx[ns + 2];
  const float* x3 = sx[ns + 3];
  #pragma unroll 4
  for (int k = 0; k < DIN; k++) {
    float4 wl = *(const float4*)(sWl + k * 64 + c4);
    float4 wr = *(const float4*)(sWr + k * 64 + c4);
    float a = x0[k], bb = x1[k], c = x2[k], dd = x3[k];
    L0.x = fmaf(a, wl.x, L0.x);  L0.y = fmaf(a, wl.y, L0.y);
    L0.z = fmaf(a, wl.z, L0.z);  L0.w = fmaf(a, wl.w, L0.w);
    R0.x = fmaf(a, wr.x, R0.x);  R0.y = fmaf(a, wr.y, R0.y);
    R0.z = fmaf(a, wr.z, R0.z);  R0.w = fmaf(a, wr.w, R0.w);
    L1.x = fmaf(bb, wl.x, L1.x); L1.y = fmaf(bb, wl.y, L1.y);
    L1.z = fmaf(bb, wl.z, L1.z); L1.w = fmaf(bb, wl.w, L1.w);
    R1.x = fmaf(bb, wr.x, R1.x); R1.y = fmaf(bb, wr.y, R1.y);
    R1.z = fmaf(bb, wr.z, R1.z); R1.w = fmaf(bb, wr.w, R1.w);
    L2.x = fmaf(c, wl.x, L2.x);  L2.y = fmaf(c, wl.y, L2.y);
    L2.z = fmaf(c, wl.z, L2.z);  L2.w = fmaf(c, wl.w, L2.w);
    R2.x = fmaf(c, wr.x, R2.x);  R2.y = fmaf(c, wr.y, R2.y);
    R2.z = fmaf(c, wr.z, R2.z);  R2.w = fmaf(c, wr.w, R2.w);
    L3.x = fmaf(dd, wl.x, L3.x); L3.y = fmaf(dd, wl.y, L3.y);
    L3.z = fmaf(dd, wl.z, L3.z); L3.w = fmaf(dd, wl.w, L3.w);
    R3.x = fmaf(dd, wr.x, R3.x); R3.y = fmaf(dd, wr.y, R3.y);
    R3.z = fmaf(dd, wr.z, R3.z); R3.w = fmaf(dd, wr.w, R3.w);
  }
  int g = nb + ns;
  if (g + 0 < nNodes) { *(float4*)(xl + (size_t)(g+0)*64 + c4) = L0; *(float4*)(xr + (size_t)(g+0)*64 + c4) = R0; }
  if (g + 1 < nNodes) { *(float4*)(xl + (size_t)(g+1)*64 + c4) = L1; *(float4*)(xr + (size_t)(g+1)*64 + c4) = R1; }
  if (g + 2 < nNodes) { *(float4*)(xl + (size_t)(g+2)*64 + c4) = L2; *(float4*)(xr + (size_t)(g+2)*64 + c4) = R2; }
  if (g + 3 < nNodes) { *(float4*)(xl + (size_t)(g+3)*64 + c4) = L3; *(float4*)(xr + (size_t)(g+3)*64 + c4) = R3; }
}

// Fused score + online softmax + aggregate.  One wave per node, chunk = 16,
// zero LDS, register aggregate with zero alpha shuffles.  (FROZEN.)
#define SC1(T, EA, OUT) { float u, acc; \
  u = T.x + fmaf(EA, We4.x, xr4.x); u = fmaxf(u, 0.2f * u); acc = at4.x * u; \
  u = T.y + fmaf(EA, We4.y, xr4.y); u = fmaxf(u, 0.2f * u); acc = fmaf(at4.y, u, acc); \
  u = T.z + fmaf(EA, We4.z, xr4.z); u = fmaxf(u, 0.2f * u); acc = fmaf(at4.z, u, acc); \
  u = T.w + fmaf(EA, We4.w, xr4.w); u = fmaxf(u, 0.2f * u); acc = fmaf(at4.w, u, acc); \
  OUT = acc; }

__global__ void __launch_bounds__(256, 5) k_edge(
    const float* __restrict__ xl, const float* __restrict__ xr,
    const int* __restrict__ rowptr, const int2* __restrict__ pairs,
    const float* __restrict__ We, const float* __restrict__ att,
    const float* __restrict__ bo, float* __restrict__ xout, int nNodes) {
  int lane = threadIdx.x & 63;
  int wv = rfl((int)(threadIdx.x >> 6));
  int n = rfl(blockIdx.x * 4 + wv);
  if (n >= nNodes) return;
  int c4 = lane & 15;   // channel group
  int r  = lane >> 4;   // edge subgroup (0..3); lane owns edges {4i+r}
  int cb = c4 * 4;      // first channel

  float4 We4 = *(const float4*)(We + cb);
  float4 at4 = *(const float4*)(att + cb);
  float4 xr4 = *(const float4*)(xr + (size_t)n * 64 + cb);
  int s0 = rfl(rowptr[n]);
  int s1 = rfl(rowptr[n + 1]);
  int last = s1 - 1;

  float m = -3.0e38f, d = 0.f;
  float4 A = {0.f, 0.f, 0.f, 0.f};

  for (int kb = s0; kb < s1; kb += 16) {
    int cnt = rfl(min(16, s1 - kb));
    // each lane loads its own 4 edge records (same-r lanes broadcast)
    int2 p0 = pairs[min(kb + r,      last)];
    int2 p1 = pairs[min(kb + 4 + r,  last)];
    int2 p2 = pairs[min(kb + 8 + r,  last)];
    int2 p3 = pairs[min(kb + 12 + r, last)];
    float ea0 = __int_as_float(p0.y);
    float ea1 = __int_as_float(p1.y);
    float ea2 = __int_as_float(p2.y);
    float ea3 = __int_as_float(p3.y);

    // coalesced row gathers: 16 same-r lanes cover the full 256B row
    float4 t0 = *(const float4*)(xl + (size_t)(unsigned)p0.x * 64 + cb);
    float4 t1 = *(const float4*)(xl + (size_t)(unsigned)p1.x * 64 + cb);
    float4 t2 = *(const float4*)(xl + (size_t)(unsigned)p2.x * 64 + cb);
    float4 t3 = *(const float4*)(xl + (size_t)(unsigned)p3.x * 64 + cb);

    // per-lane 4-channel partial dots
    float sc0, sc1, sc2, sc3;
    SC1(t0, ea0, sc0)
    SC1(t1, ea1, sc1)
    SC1(t2, ea2, sc2)
    SC1(t3, ea3, sc3)

    // complete the dots: butterfly over the 16 c4-lanes
    #pragma unroll
    for (int o = 1; o <= 8; o <<= 1) {
      sc0 += __shfl_xor(sc0, o, 64);
      sc1 += __shfl_xor(sc1, o, 64);
      sc2 += __shfl_xor(sc2, o, 64);
      sc3 += __shfl_xor(sc3, o, 64);
    }
    // mask padded edges (4i + r >= cnt) -> alpha = 0
    sc0 = (r < cnt)      ? sc0 : -3.0e38f;
    sc1 = (4 + r < cnt)  ? sc1 : -3.0e38f;
    sc2 = (8 + r < cnt)  ? sc2 : -3.0e38f;
    sc3 = (12 + r < cnt) ? sc3 : -3.0e38f;

    // online softmax (cross-lane only over r: offsets 16, 32)
    float mc = fmaxf(fmaxf(sc0, sc1), fmaxf(sc2, sc3));
    mc = fmaxf(mc, __shfl_xor(mc, 16, 64));
    mc = fmaxf(mc, __shfl_xor(mc, 32, 64));
    float newm = fmaxf(m, mc);
    float rf = __expf(m - newm);     // 0 on first chunk, 1 if max unchanged
    float a0 = __expf(sc0 - newm);
    float a1 = __expf(sc1 - newm);
    float a2 = __expf(sc2 - newm);
    float a3 = __expf(sc3 - newm);
    float ds = (a0 + a1) + (a2 + a3);
    ds += __shfl_xor(ds, 16, 64);
    ds += __shfl_xor(ds, 32, 64);
    d = d * rf + ds;
    m = newm;

    // aggregate in registers: this lane computed its own alphas
    A.x = fmaf(a0, t0.x, A.x * rf); A.y = fmaf(a0, t0.y, A.y * rf);
    A.z = fmaf(a0, t0.z, A.z * rf); A.w = fmaf(a0, t0.w, A.w * rf);
    A.x = fmaf(a1, t1.x, A.x); A.y = fmaf(a1, t1.y, A.y);
    A.z = fmaf(a1, t1.z, A.z); A.w = fmaf(a1, t1.w, A.w);
    A.x = fmaf(a2, t2.x, A.x); A.y = fmaf(a2, t2.y, A.y);
    A.z = fmaf(a2, t2.z, A.z); A.w = fmaf(a2, t2.w, A.w);
    A.x = fmaf(a3, t3.x, A.x); A.y = fmaf(a3, t3.y, A.y);
    A.z = fmaf(a3, t3.z, A.z); A.w = fmaf(a3, t3.w, A.w);
  }

  // combine the 4 r-subgroups (8 shuffles per node)
  A.x += __shfl_xor(A.x, 16, 64); A.y += __shfl_xor(A.y, 16, 64);
  A.z += __shfl_xor(A.z, 16, 64); A.w += __shfl_xor(A.w, 16, 64);
  A.x += __shfl_xor(A.x, 32, 64); A.y += __shfl_xor(A.y, 32, 64);
  A.z += __shfl_xor(A.z, 32, 64); A.w += __shfl_xor(A.w, 32, 64);

  float inv = 1.f / (d + 1e-16f);
  if (r == 0) {  // 16 lanes, contiguous 256B -> fully coalesced store
    float4 bo4 = *(const float4*)(bo + cb);
    float4 o4;
    o4.x = fmaxf(fmaf(A.x, inv, bo4.x), 0.f);
    o4.y = fmaxf(fmaf(A.y, inv, bo4.y), 0.f);
    o4.z = fmaxf(fmaf(A.z, inv, bo4.z), 0.f);
    o4.w = fmaxf(fmaf(A.w, inv, bo4.w), 0.f);
    *(float4*)(xout + (size_t)n * 64 + cb) = o4;
  }
}

__global__ void k_mean(const float* __restrict__ x, double* __restrict__ meanbuf, int nNodes) {
  __shared__ float sacc[256];
  int lane = threadIdx.x & 63;
  int wv = threadIdx.x >> 6;
  int gw = blockIdx.x * 4 + wv;
  int stride = gridDim.x * 4;
  float acc = 0.f;
  for (int n = gw; n < nNodes; n += stride) acc += x[(size_t)n * 64 + lane];
  sacc[threadIdx.x] = acc;
  __syncthreads();
  if (threadIdx.x < 64) {
    float a = sacc[threadIdx.x] + sacc[threadIdx.x + 64] + sacc[threadIdx.x + 128] + sacc[threadIdx.x + 192];
    atomicAdd(&meanbuf[lane], (double)a);
  }
}

__global__ void k_mlp(const double* __restrict__ meanbuf,
                      const float* __restrict__ Wm1, const float* __restrict__ bm1,
                      const float* __restrict__ Wm2, const float* __restrict__ bm2,
                      const float* __restrict__ Wm3, const float* __restrict__ bm3,
                      float* __restrict__ out, double invN) {
  __shared__ float xm[64];
  __shared__ float h1[32];
  __shared__ float h2[16];
  int t = threadIdx.x;
  xm[t] = (float)(meanbuf[t] * invN);
  __syncthreads();
  if (t < 32) {
    float a = bm1[t];
    for (int c = 0; c < 64; c++) a = fmaf(xm[c], Wm1[c * 32 + t], a);
    h1[t] = fmaxf(a, 0.f);
  }
  __syncthreads();
  if (t < 16) {
    float a = bm2[t];
    for (int c = 0; c < 32; c++) a = fmaf(h1[c], Wm2[c * 16 + t], a);
    h2[t] = fmaxf(a, 0.f);
  }
  __syncthreads();
  if (t == 0) {
    float a = bm3[0];
    for (int c = 0; c < 16; c++) a = fmaf(h2[c], Wm3[c], a);
    out[0] = a;
  }
}

extern "C" void kernel_launch(void* const* d_in, const int* in_sizes, int n_in,
                              void* d_out, int out_size, void* d_ws, size_t ws_size,
                              hipStream_t stream) {
  (void)n_in; (void)out_size; (void)ws_size;
  const int N = in_sizes[0] / 36;   // 50000
  const int E = in_sizes[1];        // 1600000

  const float* feat = (const float*)d_in[0];
  const float* eat  = (const float*)d_in[1];
  const int*   eidx = (const int*)d_in[2];
  const int* src = eidx;
  const int* dst = eidx + E;

  const float* L[4][7];  // Wl, bl, Wr, br, We, att, bo
  for (int l = 0; l < 4; l++)
    for (int j = 0; j < 7; j++) L[l][j] = (const float*)d_in[3 + l * 7 + j];
  const float* Wm1 = (const float*)d_in[31];
  const float* bm1 = (const float*)d_in[32];
  const float* Wm2 = (const float*)d_in[33];
  const float* bm2 = (const float*)d_in[34];
  const float* Wm3 = (const float*)d_in[35];
  const float* bm3 = (const float*)d_in[36];

  const int NBK = (N + 255) >> 8;  // buckets of 256 dst nodes (196)

  // workspace layout (512B aligned)
  char* ws = (char*)d_ws;
  size_t off = 0;
  auto alloc = [&](size_t bytes) {
    off = (off + 511) & ~(size_t)511;
    void* p = ws + off;
    off += bytes;
    return p;
  };
  int*    bcur    = (int*)alloc((size_t)NBK * 16 * 4);  // 1 counter per 64B line
  double* meanbuf = (double*)alloc(64 * 8);
  size_t zero_bytes = off;  // bcur + meanbuf
  int*    rowptr  = (int*)alloc((size_t)(N + 1) * 4);
  int2*   pairs   = (int2*)alloc((size_t)E * 8);
  float*  xA      = (float*)alloc((size_t)N * 64 * 4);  // xl
  float*  xB      = (float*)alloc((size_t)N * 64 * 4);  // xr
  uint2*  tmp     = (uint2*)alloc((size_t)NBK * BCAP * 8);  // 14.45 MB
  // xC aliases tmp (tmp dead after k_csr; xC first written by k_edge L1).
  float*  xC      = (float*)tmp;

  hipMemsetAsync(d_ws, 0, zero_bytes, stream);

  int SG = (E + 2047) / 2048;    // scatter blocks (2048 edges each)
  int TG = (N + 63) / 64;        // transform blocks (64 nodes each)
  int tgrid = TG;
  int ngrid = (N + 3) / 4;       // k_edge: 4 nodes (waves) per 256-thr block

  k_build1<<<SG + TG, 256, 0, stream>>>(src, dst, eat, bcur, tmp, E, NBK, SG,
                                        feat, L[0][0], L[0][1], L[0][2], L[0][3],
                                        xA, xB, N);
  k_csr<<<NBK, 1024, 0, stream>>>(bcur, tmp, pairs, rowptr, N, NBK);
  k_edge<<<ngrid, 256, 0, stream>>>(xA, xB, rowptr, pairs,
                                    L[0][4], L[0][5], L[0][6], xC, N);

  for (int l = 1; l < 4; l++) {
    k_transform<64><<<tgrid, 256, 0, stream>>>(xC, L[l][0], L[l][1], L[l][2], L[l][3], xA, xB, N);
    k_edge<<<ngrid, 256, 0, stream>>>(xA, xB, rowptr, pairs,
                                      L[l][4], L[l][5], L[l][6], xC, N);
  }

  k_mean<<<256, 256, 0, stream>>>(xC, meanbuf, N);
  k_mlp<<<1, 64, 0, stream>>>(meanbuf, Wm1, bm1, Wm2, bm2, Wm3, bm3, (float*)d_out, 1.0 / (double)N);
}